// Round 1
// baseline (4132.118 us; speedup 1.0000x reference)
//
#include <hip/hip_runtime.h>

#define NN 20000     // nodes per graph
#define NE 320000    // edges per graph
#define NB 2         // graphs
#define HDIM 256     // hidden
#define NDIM 64      // node feature dim
#define EDIM 32      // edge feature dim
#define NL 4         // layers

__device__ __forceinline__ float gelu_af(float x) {
    // jax.nn.gelu approximate=True (tanh form)
    float u = 0.7978845608028654f * (x + 0.044715f * x * x * x);
    float e = __expf(2.0f * u);               // inf-safe: e=inf -> t=1
    float t = 1.0f - 2.0f / (e + 1.0f);
    return 0.5f * x * (1.0f + t);
}

// ---------------- GEMM: C[M,N] = epilogue(A[M,K]@W[K,N] (+ A2@W2)) ----------
// MODE 0: C = A@W + bias(optional)
// MODE 1: C = A@W + degf[m]*bias          (aggregate: Sagg@W2 + deg*b2)
// MODE 2: C = gelu(A@W + A2@W2 + bias)    (update MLP first layer, K-split)
// MODE 3: C = C + A@W + bias              (residual h += U@V2 + c2)
template <int MODE>
__global__ __launch_bounds__(256) void gemm_k(
    const float* __restrict__ A, const float* __restrict__ W,
    const float* __restrict__ A2, const float* __restrict__ W2,
    const float* __restrict__ bias, const float* __restrict__ degf,
    float* __restrict__ C, int M, int N, int K, int K2)
{
    __shared__ float As[16][64];   // transposed A tile [k][m]
    __shared__ float Bs[16][64];   // W tile [k][n]
    const int tid = threadIdx.x;
    const int bm = blockIdx.x * 64;
    const int bn = blockIdx.y * 64;
    const int tx = tid & 15, ty = tid >> 4;
    const int ar = tid >> 2, ak = (tid & 3) * 4;     // A load: row ar, k ak..ak+3
    const int wk = tid >> 4, wn = (tid & 15) * 4;    // W load: row wk, n wn..wn+3

    float acc[4][4] = {};
    const int t1 = K >> 4;
    const int t2 = K2 >> 4;

    for (int t = 0; t < t1 + t2; ++t) {
        const float* Ap; const float* Wp; int k0, lda;
        if (t < t1) { Ap = A;  Wp = W;  k0 = t * 16;        lda = K;  }
        else        { Ap = A2; Wp = W2; k0 = (t - t1) * 16; lda = K2; }

        int m = bm + ar;
        float4 av = make_float4(0.f, 0.f, 0.f, 0.f);
        if (m < M) av = *(const float4*)&Ap[(size_t)m * lda + k0 + ak];
        As[ak + 0][ar] = av.x; As[ak + 1][ar] = av.y;
        As[ak + 2][ar] = av.z; As[ak + 3][ar] = av.w;

        float4 wv = *(const float4*)&Wp[(size_t)(k0 + wk) * N + bn + wn];
        *(float4*)&Bs[wk][wn] = wv;
        __syncthreads();

        #pragma unroll
        for (int k = 0; k < 16; ++k) {
            float4 a = *(const float4*)&As[k][ty * 4];
            float4 b = *(const float4*)&Bs[k][tx * 4];
            acc[0][0] = fmaf(a.x, b.x, acc[0][0]); acc[0][1] = fmaf(a.x, b.y, acc[0][1]);
            acc[0][2] = fmaf(a.x, b.z, acc[0][2]); acc[0][3] = fmaf(a.x, b.w, acc[0][3]);
            acc[1][0] = fmaf(a.y, b.x, acc[1][0]); acc[1][1] = fmaf(a.y, b.y, acc[1][1]);
            acc[1][2] = fmaf(a.y, b.z, acc[1][2]); acc[1][3] = fmaf(a.y, b.w, acc[1][3]);
            acc[2][0] = fmaf(a.z, b.x, acc[2][0]); acc[2][1] = fmaf(a.z, b.y, acc[2][1]);
            acc[2][2] = fmaf(a.z, b.z, acc[2][2]); acc[2][3] = fmaf(a.z, b.w, acc[2][3]);
            acc[3][0] = fmaf(a.w, b.x, acc[3][0]); acc[3][1] = fmaf(a.w, b.y, acc[3][1]);
            acc[3][2] = fmaf(a.w, b.z, acc[3][2]); acc[3][3] = fmaf(a.w, b.w, acc[3][3]);
        }
        __syncthreads();
    }

    #pragma unroll
    for (int i = 0; i < 4; ++i) {
        int m = bm + ty * 4 + i;
        if (m >= M) break;
        int n = bn + tx * 4;
        size_t cb = (size_t)m * N + n;
        float v[4];
        #pragma unroll
        for (int j = 0; j < 4; ++j) v[j] = acc[i][j];

        if (MODE == 0) {
            if (bias) {
                #pragma unroll
                for (int j = 0; j < 4; ++j) v[j] += bias[n + j];
            }
        } else if (MODE == 1) {
            float dg = degf[m];
            #pragma unroll
            for (int j = 0; j < 4; ++j) v[j] += dg * bias[n + j];
        } else if (MODE == 2) {
            #pragma unroll
            for (int j = 0; j < 4; ++j) v[j] = gelu_af(v[j] + bias[n + j]);
        } else { // MODE == 3
            float4 c = *(const float4*)&C[cb];
            v[0] += c.x + bias[n + 0]; v[1] += c.y + bias[n + 1];
            v[2] += c.z + bias[n + 2]; v[3] += c.w + bias[n + 3];
        }
        float4 o = make_float4(v[0], v[1], v[2], v[3]);
        *(float4*)&C[cb] = o;
    }
}

// ---------------- CSR build (counting sort by destination) -----------------
__global__ void hist_k(const int* __restrict__ ei, int* __restrict__ cnt) {
    int i = blockIdx.x * blockDim.x + threadIdx.x;
    if (i < NE) atomicAdd(&cnt[ei[2 * i + 1]], 1);
}

__global__ void scan_k(const int* __restrict__ cnt, int* __restrict__ row_ptr,
                       int* __restrict__ cursor, float* __restrict__ degf) {
    __shared__ int part[256];
    int tid = threadIdx.x;
    const int per = (NN + 255) >> 8;
    int s0 = tid * per;
    int s1 = s0 + per; if (s1 > NN) s1 = NN; if (s0 > NN) s0 = NN;
    int sum = 0;
    for (int i = s0; i < s1; ++i) sum += cnt[i];
    part[tid] = sum;
    __syncthreads();
    if (tid == 0) {
        int r = 0;
        for (int i = 0; i < 256; ++i) { int v = part[i]; part[i] = r; r += v; }
    }
    __syncthreads();
    int off = part[tid];
    for (int i = s0; i < s1; ++i) {
        int c = cnt[i];
        row_ptr[i] = off; cursor[i] = off; degf[i] = (float)c;
        off += c;
    }
    if (tid == 255) row_ptr[NN] = off;   // == NE
}

__global__ void fill_k(const int* __restrict__ ei, int* __restrict__ cursor,
                       int* __restrict__ csr_src, int* __restrict__ csr_eid) {
    int i = blockIdx.x * blockDim.x + threadIdx.x;
    if (i < NE) {
        int s = ei[2 * i + 0];
        int d = ei[2 * i + 1];
        int pos = atomicAdd(&cursor[d], 1);
        csr_src[pos] = s;
        csr_eid[pos] = i;
    }
}

// ---------------- Edge aggregation ------------------------------------------
// Sagg[d] = sum_{e: dst=d} gelu( Hs[src_e] + Hdb[d] + efeat[e]@W1c )
// one wave per node; lane covers 4 channels; W1c (32x256) in LDS.
__global__ __launch_bounds__(256) void edge_agg_k(
    const float* __restrict__ Hs, const float* __restrict__ Hdb,
    const float* __restrict__ efeat, const float* __restrict__ W1c,
    const int* __restrict__ csr_src, const int* __restrict__ csr_eid,
    const int* __restrict__ row_ptr, float* __restrict__ Sagg)
{
    __shared__ float w1c[EDIM * HDIM];   // 32 KiB
    const int tid = threadIdx.x;
    for (int i = tid; i < EDIM * HDIM / 4; i += 256)
        ((float4*)w1c)[i] = ((const float4*)W1c)[i];
    __syncthreads();

    const int wave = tid >> 6, lane = tid & 63;
    const int d = blockIdx.x * 4 + wave;
    if (d >= NN) return;
    const int start = row_ptr[d], end = row_ptr[d + 1];
    const int c0 = lane * 4;

    const float4 hd = *(const float4*)&Hdb[(size_t)d * HDIM + c0];
    float a0 = 0.f, a1 = 0.f, a2 = 0.f, a3 = 0.f;

    for (int p = start; p < end; ++p) {
        int s   = csr_src[p];
        int eid = csr_eid[p];
        float4 hs = *(const float4*)&Hs[(size_t)s * HDIM + c0];
        float efv = efeat[(size_t)eid * EDIM + (lane & 31)];
        float e0 = 0.f, e1 = 0.f, e2 = 0.f, e3 = 0.f;
        #pragma unroll
        for (int k = 0; k < EDIM; ++k) {
            float efk = __shfl(efv, k, 64);
            float4 wv = *(const float4*)&w1c[k * HDIM + c0];
            e0 = fmaf(efk, wv.x, e0); e1 = fmaf(efk, wv.y, e1);
            e2 = fmaf(efk, wv.z, e2); e3 = fmaf(efk, wv.w, e3);
        }
        a0 += gelu_af(hs.x + hd.x + e0);
        a1 += gelu_af(hs.y + hd.y + e1);
        a2 += gelu_af(hs.z + hd.z + e2);
        a3 += gelu_af(hs.w + hd.w + e3);
    }
    float4 o = make_float4(a0, a1, a2, a3);
    *(float4*)&Sagg[(size_t)d * HDIM + c0] = o;
}

// ---------------- launcher ---------------------------------------------------
extern "C" void kernel_launch(void* const* d_in, const int* in_sizes, int n_in,
                              void* d_out, int out_size, void* d_ws, size_t ws_size,
                              hipStream_t stream)
{
    const float* nf    = (const float*)d_in[0];
    const int*   ei    = (const int*)  d_in[1];
    const float* efeat = (const float*)d_in[2];
    const float* inW   = (const float*)d_in[3];
    const float* inb   = (const float*)d_in[4];
    const float* mW1   = (const float*)d_in[5];
    const float* mb1   = (const float*)d_in[6];
    const float* mW2   = (const float*)d_in[7];
    const float* mb2   = (const float*)d_in[8];
    const float* uW1   = (const float*)d_in[9];
    const float* ub1   = (const float*)d_in[10];
    const float* uW2   = (const float*)d_in[11];
    const float* ub2   = (const float*)d_in[12];
    const float* outW  = (const float*)d_in[13];
    const float* outb  = (const float*)d_in[14];
    float* outp = (float*)d_out;

    char* p = (char*)d_ws;
    auto carve = [&](size_t bytes) -> void* {
        void* r = (void*)p;
        p += (bytes + 255) & ~(size_t)255;
        return r;
    };
    float* h   = (float*)carve((size_t)NN * HDIM * 4);
    float* T1  = (float*)carve((size_t)NN * HDIM * 4);
    float* T2  = (float*)carve((size_t)NN * HDIM * 4);
    float* T3  = (float*)carve((size_t)NN * HDIM * 4);
    int* csr_src = (int*)carve((size_t)NE * 4);
    int* csr_eid = (int*)carve((size_t)NE * 4);
    int* row_ptr = (int*)carve((size_t)(NN + 1) * 4);
    int* cursor  = (int*)carve((size_t)NN * 4);
    int* cnt     = (int*)carve((size_t)NN * 4);
    float* degf  = (float*)carve((size_t)NN * 4);
    (void)ws_size; (void)in_sizes; (void)n_in; (void)out_size;

    const dim3 blk(256);
    const dim3 gemm_g(313, HDIM / 64);   // M=20000 -> 313 tiles of 64
    const dim3 gemm_go(313, NDIM / 64);

    for (int g = 0; g < NB; ++g) {
        const float* nf_g = nf    + (size_t)g * NN * NDIM;
        const int*   ei_g = ei    + (size_t)g * NE * 2;
        const float* ef_g = efeat + (size_t)g * NE * EDIM;
        float*      out_g = outp  + (size_t)g * NN * NDIM;

        // CSR by destination (same for all layers)
        hipMemsetAsync(cnt, 0, NN * sizeof(int), stream);
        hist_k<<<(NE + 255) / 256, blk, 0, stream>>>(ei_g, cnt);
        scan_k<<<1, blk, 0, stream>>>(cnt, row_ptr, cursor, degf);
        fill_k<<<(NE + 255) / 256, blk, 0, stream>>>(ei_g, cursor, csr_src, csr_eid);

        // h = nf @ in_W + in_b
        gemm_k<0><<<gemm_g, blk, 0, stream>>>(nf_g, inW, nullptr, nullptr,
                                              inb, nullptr, h, NN, HDIM, NDIM, 0);

        for (int l = 0; l < NL; ++l) {
            const float* W1 = mW1 + (size_t)l * (2 * HDIM + EDIM) * HDIM;
            const float* W2 = mW2 + (size_t)l * HDIM * HDIM;
            const float* V1 = uW1 + (size_t)l * 2 * HDIM * HDIM;
            const float* V2 = uW2 + (size_t)l * HDIM * HDIM;

            // Hs = h @ W1[0:256]            (T1)
            gemm_k<0><<<gemm_g, blk, 0, stream>>>(h, W1, nullptr, nullptr,
                                                  nullptr, nullptr, T1, NN, HDIM, HDIM, 0);
            // Hd = h @ W1[256:512] + b1     (T2)
            gemm_k<0><<<gemm_g, blk, 0, stream>>>(h, W1 + HDIM * HDIM, nullptr, nullptr,
                                                  mb1 + l * HDIM, nullptr, T2, NN, HDIM, HDIM, 0);
            // Sagg[d] = sum gelu(Hs[s]+Hd[d]+ef@W1c)   (T3)
            edge_agg_k<<<NN / 4, blk, 0, stream>>>(T1, T2, ef_g, W1 + 2 * HDIM * HDIM,
                                                   csr_src, csr_eid, row_ptr, T3);
            // agg = Sagg @ W2 + deg*b2      (T1)
            gemm_k<1><<<gemm_g, blk, 0, stream>>>(T3, W2, nullptr, nullptr,
                                                  mb2 + l * HDIM, degf, T1, NN, HDIM, HDIM, 0);
            // U = gelu(h@V1a + agg@V1b + c1) (T2)
            gemm_k<2><<<gemm_g, blk, 0, stream>>>(h, V1, T1, V1 + HDIM * HDIM,
                                                  ub1 + l * HDIM, nullptr, T2, NN, HDIM, HDIM, HDIM);
            // h += U @ V2 + c2
            gemm_k<3><<<gemm_g, blk, 0, stream>>>(T2, V2, nullptr, nullptr,
                                                  ub2 + l * HDIM, nullptr, h, NN, HDIM, HDIM, 0);
        }

        // out = h @ out_W + out_b
        gemm_k<0><<<gemm_go, blk, 0, stream>>>(h, outW, nullptr, nullptr,
                                               outb, nullptr, out_g, NN, NDIM, HDIM, 0);
    }
}

// Round 2
// 3786.146 us; speedup vs baseline: 1.0914x; 1.0914x over previous
//
#include <hip/hip_runtime.h>

#define NN 20000     // nodes per graph
#define NE 320000    // edges per graph
#define NB 2         // graphs
#define HDIM 256     // hidden
#define NDIM 64      // node feature dim
#define EDIM 32      // edge feature dim
#define NL 4         // layers

__device__ __forceinline__ float gelu_af(float x) {
    // jax.nn.gelu approximate=True (tanh form)
    float u = 0.7978845608028654f * (x + 0.044715f * x * x * x);
    float e = __expf(2.0f * u);               // inf-safe: e=inf -> t=1
    float t = 1.0f - 2.0f / (e + 1.0f);
    return 0.5f * x * (1.0f + t);
}

// ---------------- GEMM: C[M,N] = epilogue(A[M,K]@W[K,N] (+ A2@W2)) ----------
// MODE 0: C = A@W + bias(optional)
// MODE 1: C = A@W + degf[m]*bias          (aggregate: Sagg@W2 + deg*b2)
// MODE 2: C = gelu(A@W + A2@W2 + bias)    (update MLP first layer, K-split)
// MODE 3: C = C + A@W + bias              (residual h += U@V2 + c2)
template <int MODE>
__global__ __launch_bounds__(256) void gemm_k(
    const float* __restrict__ A, const float* __restrict__ W,
    const float* __restrict__ A2, const float* __restrict__ W2,
    const float* __restrict__ bias, const float* __restrict__ degf,
    float* __restrict__ C, int M, int N, int K, int K2)
{
    __shared__ float As[16][64];   // transposed A tile [k][m]
    __shared__ float Bs[16][64];   // W tile [k][n]
    const int tid = threadIdx.x;
    const int bm = blockIdx.x * 64;
    const int bn = blockIdx.y * 64;
    const int tx = tid & 15, ty = tid >> 4;
    const int ar = tid >> 2, ak = (tid & 3) * 4;     // A load: row ar, k ak..ak+3
    const int wk = tid >> 4, wn = (tid & 15) * 4;    // W load: row wk, n wn..wn+3

    float acc[4][4] = {};
    const int t1 = K >> 4;
    const int t2 = K2 >> 4;

    for (int t = 0; t < t1 + t2; ++t) {
        const float* Ap; const float* Wp; int k0, lda;
        if (t < t1) { Ap = A;  Wp = W;  k0 = t * 16;        lda = K;  }
        else        { Ap = A2; Wp = W2; k0 = (t - t1) * 16; lda = K2; }

        int m = bm + ar;
        float4 av = make_float4(0.f, 0.f, 0.f, 0.f);
        if (m < M) av = *(const float4*)&Ap[(size_t)m * lda + k0 + ak];
        As[ak + 0][ar] = av.x; As[ak + 1][ar] = av.y;
        As[ak + 2][ar] = av.z; As[ak + 3][ar] = av.w;

        float4 wv = *(const float4*)&Wp[(size_t)(k0 + wk) * N + bn + wn];
        *(float4*)&Bs[wk][wn] = wv;
        __syncthreads();

        #pragma unroll
        for (int k = 0; k < 16; ++k) {
            float4 a = *(const float4*)&As[k][ty * 4];
            float4 b = *(const float4*)&Bs[k][tx * 4];
            acc[0][0] = fmaf(a.x, b.x, acc[0][0]); acc[0][1] = fmaf(a.x, b.y, acc[0][1]);
            acc[0][2] = fmaf(a.x, b.z, acc[0][2]); acc[0][3] = fmaf(a.x, b.w, acc[0][3]);
            acc[1][0] = fmaf(a.y, b.x, acc[1][0]); acc[1][1] = fmaf(a.y, b.y, acc[1][1]);
            acc[1][2] = fmaf(a.y, b.z, acc[1][2]); acc[1][3] = fmaf(a.y, b.w, acc[1][3]);
            acc[2][0] = fmaf(a.z, b.x, acc[2][0]); acc[2][1] = fmaf(a.z, b.y, acc[2][1]);
            acc[2][2] = fmaf(a.z, b.z, acc[2][2]); acc[2][3] = fmaf(a.z, b.w, acc[2][3]);
            acc[3][0] = fmaf(a.w, b.x, acc[3][0]); acc[3][1] = fmaf(a.w, b.y, acc[3][1]);
            acc[3][2] = fmaf(a.w, b.z, acc[3][2]); acc[3][3] = fmaf(a.w, b.w, acc[3][3]);
        }
        __syncthreads();
    }

    #pragma unroll
    for (int i = 0; i < 4; ++i) {
        int m = bm + ty * 4 + i;
        if (m >= M) break;
        int n = bn + tx * 4;
        size_t cb = (size_t)m * N + n;
        float v[4];
        #pragma unroll
        for (int j = 0; j < 4; ++j) v[j] = acc[i][j];

        if (MODE == 0) {
            if (bias) {
                #pragma unroll
                for (int j = 0; j < 4; ++j) v[j] += bias[n + j];
            }
        } else if (MODE == 1) {
            float dg = degf[m];
            #pragma unroll
            for (int j = 0; j < 4; ++j) v[j] += dg * bias[n + j];
        } else if (MODE == 2) {
            #pragma unroll
            for (int j = 0; j < 4; ++j) v[j] = gelu_af(v[j] + bias[n + j]);
        } else { // MODE == 3
            float4 c = *(const float4*)&C[cb];
            v[0] += c.x + bias[n + 0]; v[1] += c.y + bias[n + 1];
            v[2] += c.z + bias[n + 2]; v[3] += c.w + bias[n + 3];
        }
        float4 o = make_float4(v[0], v[1], v[2], v[3]);
        *(float4*)&C[cb] = o;
    }
}

// ---------------- CSR build (counting sort by destination) -----------------
__global__ void hist_k(const int* __restrict__ ei, int* __restrict__ cnt) {
    int i = blockIdx.x * blockDim.x + threadIdx.x;
    if (i < NE) atomicAdd(&cnt[ei[2 * i + 1]], 1);
}

__global__ void scan_k(const int* __restrict__ cnt, int* __restrict__ row_ptr,
                       int* __restrict__ cursor, float* __restrict__ degf) {
    __shared__ int part[256];
    int tid = threadIdx.x;
    const int per = (NN + 255) >> 8;
    int s0 = tid * per;
    int s1 = s0 + per; if (s1 > NN) s1 = NN; if (s0 > NN) s0 = NN;
    int sum = 0;
    for (int i = s0; i < s1; ++i) sum += cnt[i];
    part[tid] = sum;
    __syncthreads();
    if (tid == 0) {
        int r = 0;
        for (int i = 0; i < 256; ++i) { int v = part[i]; part[i] = r; r += v; }
    }
    __syncthreads();
    int off = part[tid];
    for (int i = s0; i < s1; ++i) {
        int c = cnt[i];
        row_ptr[i] = off; cursor[i] = off; degf[i] = (float)c;
        off += c;
    }
    if (tid == 255) row_ptr[NN] = off;   // == NE
}

__global__ void fill_k(const int* __restrict__ ei, int* __restrict__ cursor,
                       int* __restrict__ csr_src, int* __restrict__ csr_eid) {
    int i = blockIdx.x * blockDim.x + threadIdx.x;
    if (i < NE) {
        int s = ei[2 * i + 0];
        int d = ei[2 * i + 1];
        int pos = atomicAdd(&cursor[d], 1);
        csr_src[pos] = s;
        csr_eid[pos] = i;
    }
}

// ---------------- Edge aggregation ------------------------------------------
// Sagg[d] = sum_{e: dst=d} gelu( Hs[src_e] + Hdb[d] + efeat[e]@W1c )
// one wave per node; lane covers 4 channels; W1c (32x256) in LDS.
// 4-edge chunks: ILP on Hs gathers, 4x amortized W1c LDS reads, scalar
// (SGPR) efeat loads via readfirstlane (edge id is wave-uniform).
__global__ __launch_bounds__(256) void edge_agg_k(
    const float* __restrict__ Hs, const float* __restrict__ Hdb,
    const float* __restrict__ efeat, const float* __restrict__ W1c,
    const int* __restrict__ csr_src, const int* __restrict__ csr_eid,
    const int* __restrict__ row_ptr, float* __restrict__ Sagg)
{
    __shared__ float w1c[EDIM * HDIM];   // 32 KiB
    const int tid = threadIdx.x;
    for (int i = tid; i < EDIM * HDIM / 4; i += 256)
        ((float4*)w1c)[i] = ((const float4*)W1c)[i];
    __syncthreads();

    const int wave = tid >> 6, lane = tid & 63;
    const int d = blockIdx.x * 4 + wave;
    if (d >= NN) return;
    const int start = row_ptr[d], end = row_ptr[d + 1];
    const int c0 = lane * 4;

    const float4 hd = *(const float4*)&Hdb[(size_t)d * HDIM + c0];
    float4 acc = make_float4(0.f, 0.f, 0.f, 0.f);

    for (int p = start; p < end; p += 4) {
        const int nc = end - p;   // >=1; chunk covers min(nc,4)

        int sj[4], ej[4];
        #pragma unroll
        for (int j = 0; j < 4; ++j) {
            int q = p + ((j < nc) ? j : 0);          // clamp tail to valid idx
            sj[j] = __builtin_amdgcn_readfirstlane(csr_src[q]);
            ej[j] = __builtin_amdgcn_readfirstlane(csr_eid[q]);
        }

        // 4 independent 1KB row gathers issued together
        float4 hs[4];
        #pragma unroll
        for (int j = 0; j < 4; ++j)
            hs[j] = *(const float4*)&Hs[(size_t)sj[j] * HDIM + c0];

        // scalar (wave-uniform) efeat row pointers
        const float* er0 = efeat + (size_t)ej[0] * EDIM;
        const float* er1 = efeat + (size_t)ej[1] * EDIM;
        const float* er2 = efeat + (size_t)ej[2] * EDIM;
        const float* er3 = efeat + (size_t)ej[3] * EDIM;

        float4 ev[4];
        #pragma unroll
        for (int j = 0; j < 4; ++j) ev[j] = make_float4(0.f, 0.f, 0.f, 0.f);

        #pragma unroll
        for (int k = 0; k < EDIM; ++k) {
            const float4 wv = *(const float4*)&w1c[k * HDIM + c0];
            const float f0 = er0[k], f1 = er1[k], f2 = er2[k], f3 = er3[k];
            ev[0].x = fmaf(f0, wv.x, ev[0].x); ev[0].y = fmaf(f0, wv.y, ev[0].y);
            ev[0].z = fmaf(f0, wv.z, ev[0].z); ev[0].w = fmaf(f0, wv.w, ev[0].w);
            ev[1].x = fmaf(f1, wv.x, ev[1].x); ev[1].y = fmaf(f1, wv.y, ev[1].y);
            ev[1].z = fmaf(f1, wv.z, ev[1].z); ev[1].w = fmaf(f1, wv.w, ev[1].w);
            ev[2].x = fmaf(f2, wv.x, ev[2].x); ev[2].y = fmaf(f2, wv.y, ev[2].y);
            ev[2].z = fmaf(f2, wv.z, ev[2].z); ev[2].w = fmaf(f2, wv.w, ev[2].w);
            ev[3].x = fmaf(f3, wv.x, ev[3].x); ev[3].y = fmaf(f3, wv.y, ev[3].y);
            ev[3].z = fmaf(f3, wv.z, ev[3].z); ev[3].w = fmaf(f3, wv.w, ev[3].w);
        }

        #pragma unroll
        for (int j = 0; j < 4; ++j) {
            if (j < nc) {   // wave-uniform predicate
                acc.x += gelu_af(hs[j].x + hd.x + ev[j].x);
                acc.y += gelu_af(hs[j].y + hd.y + ev[j].y);
                acc.z += gelu_af(hs[j].z + hd.z + ev[j].z);
                acc.w += gelu_af(hs[j].w + hd.w + ev[j].w);
            }
        }
    }
    *(float4*)&Sagg[(size_t)d * HDIM + c0] = acc;
}

// ---------------- launcher ---------------------------------------------------
extern "C" void kernel_launch(void* const* d_in, const int* in_sizes, int n_in,
                              void* d_out, int out_size, void* d_ws, size_t ws_size,
                              hipStream_t stream)
{
    const float* nf    = (const float*)d_in[0];
    const int*   ei    = (const int*)  d_in[1];
    const float* efeat = (const float*)d_in[2];
    const float* inW   = (const float*)d_in[3];
    const float* inb   = (const float*)d_in[4];
    const float* mW1   = (const float*)d_in[5];
    const float* mb1   = (const float*)d_in[6];
    const float* mW2   = (const float*)d_in[7];
    const float* mb2   = (const float*)d_in[8];
    const float* uW1   = (const float*)d_in[9];
    const float* ub1   = (const float*)d_in[10];
    const float* uW2   = (const float*)d_in[11];
    const float* ub2   = (const float*)d_in[12];
    const float* outW  = (const float*)d_in[13];
    const float* outb  = (const float*)d_in[14];
    float* outp = (float*)d_out;

    char* p = (char*)d_ws;
    auto carve = [&](size_t bytes) -> void* {
        void* r = (void*)p;
        p += (bytes + 255) & ~(size_t)255;
        return r;
    };
    float* h   = (float*)carve((size_t)NN * HDIM * 4);
    float* T1  = (float*)carve((size_t)NN * HDIM * 4);
    float* T2  = (float*)carve((size_t)NN * HDIM * 4);
    float* T3  = (float*)carve((size_t)NN * HDIM * 4);
    int* csr_src = (int*)carve((size_t)NE * 4);
    int* csr_eid = (int*)carve((size_t)NE * 4);
    int* row_ptr = (int*)carve((size_t)(NN + 1) * 4);
    int* cursor  = (int*)carve((size_t)NN * 4);
    int* cnt     = (int*)carve((size_t)NN * 4);
    float* degf  = (float*)carve((size_t)NN * 4);
    (void)ws_size; (void)in_sizes; (void)n_in; (void)out_size;

    const dim3 blk(256);
    const dim3 gemm_g(313, HDIM / 64);   // M=20000 -> 313 tiles of 64
    const dim3 gemm_go(313, NDIM / 64);

    for (int g = 0; g < NB; ++g) {
        const float* nf_g = nf    + (size_t)g * NN * NDIM;
        const int*   ei_g = ei    + (size_t)g * NE * 2;
        const float* ef_g = efeat + (size_t)g * NE * EDIM;
        float*      out_g = outp  + (size_t)g * NN * NDIM;

        // CSR by destination (same for all layers)
        hipMemsetAsync(cnt, 0, NN * sizeof(int), stream);
        hist_k<<<(NE + 255) / 256, blk, 0, stream>>>(ei_g, cnt);
        scan_k<<<1, blk, 0, stream>>>(cnt, row_ptr, cursor, degf);
        fill_k<<<(NE + 255) / 256, blk, 0, stream>>>(ei_g, cursor, csr_src, csr_eid);

        // h = nf @ in_W + in_b
        gemm_k<0><<<gemm_g, blk, 0, stream>>>(nf_g, inW, nullptr, nullptr,
                                              inb, nullptr, h, NN, HDIM, NDIM, 0);

        for (int l = 0; l < NL; ++l) {
            const float* W1 = mW1 + (size_t)l * (2 * HDIM + EDIM) * HDIM;
            const float* W2 = mW2 + (size_t)l * HDIM * HDIM;
            const float* V1 = uW1 + (size_t)l * 2 * HDIM * HDIM;
            const float* V2 = uW2 + (size_t)l * HDIM * HDIM;

            // Hs = h @ W1[0:256]            (T1)
            gemm_k<0><<<gemm_g, blk, 0, stream>>>(h, W1, nullptr, nullptr,
                                                  nullptr, nullptr, T1, NN, HDIM, HDIM, 0);
            // Hd = h @ W1[256:512] + b1     (T2)
            gemm_k<0><<<gemm_g, blk, 0, stream>>>(h, W1 + HDIM * HDIM, nullptr, nullptr,
                                                  mb1 + l * HDIM, nullptr, T2, NN, HDIM, HDIM, 0);
            // Sagg[d] = sum gelu(Hs[s]+Hd[d]+ef@W1c)   (T3)
            edge_agg_k<<<NN / 4, blk, 0, stream>>>(T1, T2, ef_g, W1 + 2 * HDIM * HDIM,
                                                   csr_src, csr_eid, row_ptr, T3);
            // agg = Sagg @ W2 + deg*b2      (T1)
            gemm_k<1><<<gemm_g, blk, 0, stream>>>(T3, W2, nullptr, nullptr,
                                                  mb2 + l * HDIM, degf, T1, NN, HDIM, HDIM, 0);
            // U = gelu(h@V1a + agg@V1b + c1) (T2)
            gemm_k<2><<<gemm_g, blk, 0, stream>>>(h, V1, T1, V1 + HDIM * HDIM,
                                                  ub1 + l * HDIM, nullptr, T2, NN, HDIM, HDIM, HDIM);
            // h += U @ V2 + c2
            gemm_k<3><<<gemm_g, blk, 0, stream>>>(T2, V2, nullptr, nullptr,
                                                  ub2 + l * HDIM, nullptr, h, NN, HDIM, HDIM, 0);
        }

        // out = h @ out_W + out_b
        gemm_k<0><<<gemm_go, blk, 0, stream>>>(h, outW, nullptr, nullptr,
                                               outb, nullptr, out_g, NN, NDIM, HDIM, 0);
    }
}

// Round 3
// 2621.323 us; speedup vs baseline: 1.5763x; 1.4444x over previous
//
#include <hip/hip_runtime.h>

#define NN 20000     // nodes per graph
#define NE 320000    // edges per graph
#define NB 2         // graphs
#define HDIM 256     // hidden
#define NDIM 64      // node feature dim
#define EDIM 32      // edge feature dim
#define NL 4         // layers

typedef short short8 __attribute__((ext_vector_type(8)));
typedef float f32x4 __attribute__((ext_vector_type(4)));

__device__ __forceinline__ float gelu_af(float x) {
    float u = 0.7978845608028654f * (x + 0.044715f * x * x * x);
    float e = __expf(2.0f * u);
    float t = 1.0f - 2.0f / (e + 1.0f);
    return 0.5f * x * (1.0f + t);
}

__device__ __forceinline__ unsigned short f2bf(float f) {
    unsigned int x = __float_as_uint(f);
    unsigned int r = (x + 0x7fffu + ((x >> 16) & 1u)) >> 16;
    return (unsigned short)r;
}
__device__ __forceinline__ float bf2f(unsigned short h) {
    return __uint_as_float(((unsigned int)h) << 16);
}

// ---------------- weight transpose + bf16 convert (once per launch) ---------
__global__ __launch_bounds__(256) void tr_k(
    const float* __restrict__ inW, const float* __restrict__ mW1,
    const float* __restrict__ mW2, const float* __restrict__ uW1,
    const float* __restrict__ uW2, const float* __restrict__ outW,
    unsigned short* __restrict__ dst)
{
    const int id = blockIdx.z;
    const float* src; int K, N; size_t doff;
    if (id == 0)       { src = inW;  K = 64;  N = 256; doff = 0; }
    else if (id <= 4)  { int l = id - 1;  src = mW1 + (size_t)l * 544 * 256; K = 544; N = 256; doff = 16384   + (size_t)l * 139264; }
    else if (id <= 8)  { int l = id - 5;  src = mW2 + (size_t)l * 256 * 256; K = 256; N = 256; doff = 573440  + (size_t)l * 65536;  }
    else if (id <= 12) { int l = id - 9;  src = uW1 + (size_t)l * 512 * 256; K = 512; N = 256; doff = 835584  + (size_t)l * 131072; }
    else if (id <= 16) { int l = id - 13; src = uW2 + (size_t)l * 256 * 256; K = 256; N = 256; doff = 1359872 + (size_t)l * 65536;  }
    else               { src = outW; K = 256; N = 64;  doff = 1622016; }

    const int k0 = blockIdx.x * 32, n0 = blockIdx.y * 32;
    if (k0 >= K || n0 >= N) return;   // block-uniform

    __shared__ float tile[32][33];
    const int tx = threadIdx.x & 31, ty = threadIdx.x >> 5;
    #pragma unroll
    for (int i = 0; i < 4; ++i) {
        int k = k0 + ty + i * 8, n = n0 + tx;
        tile[ty + i * 8][tx] = (k < K && n < N) ? src[(size_t)k * N + n] : 0.f;
    }
    __syncthreads();
    #pragma unroll
    for (int i = 0; i < 4; ++i) {
        int n = n0 + ty + i * 8, k = k0 + tx;
        if (n < N && k < K) dst[doff + (size_t)n * K + k] = f2bf(tile[tx][ty + i * 8]);
    }
}

// ---------------- MFMA GEMM (split-A hi/lo bf16, pre-transposed bf16 B) -----
// MODE 0: C = A@W + bias(optional)        MODE 1: C = A@W + degf[m]*bias
// MODE 2: C = gelu(A@W + A2@W2 + bias)    MODE 3: C = C + A@W + bias
template <int MODE>
__global__ __launch_bounds__(256) void mgemm_k(
    const float* __restrict__ A, const unsigned short* __restrict__ BT, int ldb,
    const float* __restrict__ A2, const unsigned short* __restrict__ BT2, int ldb2,
    const float* __restrict__ bias, const float* __restrict__ degf,
    float* __restrict__ C, int M, int N, int K, int K2)
{
    __shared__ unsigned char smem[64 * 80 * 2 + 128 * 80];  // ahi, alo, bt (80B-padded rows)
    unsigned char* ahi = smem;
    unsigned char* alo = smem + 64 * 80;
    unsigned char* btl = smem + 64 * 80 * 2;

    const int tid = threadIdx.x;
    const int bm = blockIdx.x * 64;
    const int bn = blockIdx.y * 128;
    const int w = tid >> 6, lane = tid & 63;
    const int wr = w >> 1, wc = w & 1;
    const int lrow = lane & 15, lg = lane >> 4;

    f32x4 acc[2][4];
    #pragma unroll
    for (int i = 0; i < 2; ++i)
        #pragma unroll
        for (int j = 0; j < 4; ++j) acc[i][j] = (f32x4){0.f, 0.f, 0.f, 0.f};

    const int t1 = K >> 5, t2 = K2 >> 5;
    for (int t = 0; t < t1 + t2; ++t) {
        const float* Ap; const unsigned short* Bp; int k0, lda, ldbv;
        if (t < t1) { Ap = A;  Bp = BT;  k0 = t * 32;        lda = K;  ldbv = ldb;  }
        else        { Ap = A2; Bp = BT2; k0 = (t - t1) * 32; lda = K2; ldbv = ldb2; }

        {   // stage A: 64 rows x 32 k, f32 -> hi/lo bf16
            const int row = tid >> 2, kq = (tid & 3) * 8;
            const int m = bm + row;
            float4 v0 = make_float4(0.f, 0.f, 0.f, 0.f), v1 = v0;
            if (m < M) {
                v0 = *(const float4*)&Ap[(size_t)m * lda + k0 + kq];
                v1 = *(const float4*)&Ap[(size_t)m * lda + k0 + kq + 4];
            }
            float vv[8] = {v0.x, v0.y, v0.z, v0.w, v1.x, v1.y, v1.z, v1.w};
            unsigned short hh[8], ll[8];
            #pragma unroll
            for (int j = 0; j < 8; ++j) {
                hh[j] = f2bf(vv[j]);
                ll[j] = f2bf(vv[j] - bf2f(hh[j]));
            }
            ushort4 ph0 = {hh[0], hh[1], hh[2], hh[3]}, ph1 = {hh[4], hh[5], hh[6], hh[7]};
            ushort4 pl0 = {ll[0], ll[1], ll[2], ll[3]}, pl1 = {ll[4], ll[5], ll[6], ll[7]};
            *(ushort4*)(ahi + row * 80 + kq * 2)     = ph0;
            *(ushort4*)(ahi + row * 80 + kq * 2 + 8) = ph1;
            *(ushort4*)(alo + row * 80 + kq * 2)     = pl0;
            *(ushort4*)(alo + row * 80 + kq * 2 + 8) = pl1;
        }
        {   // stage B: 128 n-rows x 32 k bf16
            const int row = tid >> 1, half = tid & 1;
            const int n = bn + row;
            #pragma unroll
            for (int c = 0; c < 2; ++c) {
                const int q = half * 2 + c;
                uint4 d = make_uint4(0u, 0u, 0u, 0u);
                if (n < N) d = *(const uint4*)&Bp[(size_t)n * ldbv + k0 + q * 8];
                *(uint4*)(btl + row * 80 + q * 16) = d;
            }
        }
        __syncthreads();

        short8 ah[2], al[2], bfr[4];
        #pragma unroll
        for (int mi = 0; mi < 2; ++mi) {
            const int r = wr * 32 + mi * 16 + lrow;
            ah[mi] = *(const short8*)(ahi + r * 80 + lg * 16);
            al[mi] = *(const short8*)(alo + r * 80 + lg * 16);
        }
        #pragma unroll
        for (int ni = 0; ni < 4; ++ni) {
            const int r = wc * 64 + ni * 16 + lrow;
            bfr[ni] = *(const short8*)(btl + r * 80 + lg * 16);
        }
        #pragma unroll
        for (int mi = 0; mi < 2; ++mi)
            #pragma unroll
            for (int ni = 0; ni < 4; ++ni) {
                acc[mi][ni] = __builtin_amdgcn_mfma_f32_16x16x32_bf16(ah[mi], bfr[ni], acc[mi][ni], 0, 0, 0);
                acc[mi][ni] = __builtin_amdgcn_mfma_f32_16x16x32_bf16(al[mi], bfr[ni], acc[mi][ni], 0, 0, 0);
            }
        __syncthreads();
    }

    // epilogue: D row = 4*lg + reg, col = lrow
    #pragma unroll
    for (int mi = 0; mi < 2; ++mi) {
        #pragma unroll
        for (int ni = 0; ni < 4; ++ni) {
            const int ncol = bn + wc * 64 + ni * 16 + lrow;
            if (ncol >= N) continue;
            const float bv = bias ? bias[ncol] : 0.f;
            const int mbase = bm + wr * 32 + mi * 16 + lg * 4;
            #pragma unroll
            for (int r = 0; r < 4; ++r) {
                const int m = mbase + r;
                if (m >= M) continue;
                float v = acc[mi][ni][r];
                if (MODE == 0)      v += bv;
                else if (MODE == 1) v += degf[m] * bv;
                else if (MODE == 2) v = gelu_af(v + bv);
                else                v += C[(size_t)m * N + ncol] + bv;
                C[(size_t)m * N + ncol] = v;
            }
        }
    }
}

// ---------------- CSR build (counting sort by destination) -----------------
__global__ void hist_k(const int* __restrict__ ei, int* __restrict__ cnt) {
    int i = blockIdx.x * blockDim.x + threadIdx.x;
    if (i < NE) atomicAdd(&cnt[ei[2 * i + 1]], 1);
}

__global__ void scan_k(const int* __restrict__ cnt, int* __restrict__ row_ptr,
                       int* __restrict__ cursor, float* __restrict__ degf) {
    __shared__ int part[256];
    int tid = threadIdx.x;
    const int per = (NN + 255) >> 8;
    int s0 = tid * per;
    int s1 = s0 + per; if (s1 > NN) s1 = NN; if (s0 > NN) s0 = NN;
    int sum = 0;
    for (int i = s0; i < s1; ++i) sum += cnt[i];
    part[tid] = sum;
    __syncthreads();
    if (tid == 0) {
        int r = 0;
        for (int i = 0; i < 256; ++i) { int v = part[i]; part[i] = r; r += v; }
    }
    __syncthreads();
    int off = part[tid];
    for (int i = s0; i < s1; ++i) {
        int c = cnt[i];
        row_ptr[i] = off; cursor[i] = off; degf[i] = (float)c;
        off += c;
    }
    if (tid == 255) row_ptr[NN] = off;
}

__global__ void fill_k(const int* __restrict__ ei, int* __restrict__ cursor,
                       int* __restrict__ csr_src, int* __restrict__ csr_eid) {
    int i = blockIdx.x * blockDim.x + threadIdx.x;
    if (i < NE) {
        int s = ei[2 * i + 0];
        int d = ei[2 * i + 1];
        int pos = atomicAdd(&cursor[d], 1);
        csr_src[pos] = s;
        csr_eid[pos] = i;
    }
}

// ---------------- Edge aggregation (unchanged from R2) ----------------------
__global__ __launch_bounds__(256) void edge_agg_k(
    const float* __restrict__ Hs, const float* __restrict__ Hdb,
    const float* __restrict__ efeat, const float* __restrict__ W1c,
    const int* __restrict__ csr_src, const int* __restrict__ csr_eid,
    const int* __restrict__ row_ptr, float* __restrict__ Sagg)
{
    __shared__ float w1c[EDIM * HDIM];
    const int tid = threadIdx.x;
    for (int i = tid; i < EDIM * HDIM / 4; i += 256)
        ((float4*)w1c)[i] = ((const float4*)W1c)[i];
    __syncthreads();

    const int wave = tid >> 6, lane = tid & 63;
    const int d = blockIdx.x * 4 + wave;
    if (d >= NN) return;
    const int start = row_ptr[d], end = row_ptr[d + 1];
    const int c0 = lane * 4;

    const float4 hd = *(const float4*)&Hdb[(size_t)d * HDIM + c0];
    float4 acc = make_float4(0.f, 0.f, 0.f, 0.f);

    for (int p = start; p < end; p += 4) {
        const int nc = end - p;

        int sj[4], ej[4];
        #pragma unroll
        for (int j = 0; j < 4; ++j) {
            int q = p + ((j < nc) ? j : 0);
            sj[j] = __builtin_amdgcn_readfirstlane(csr_src[q]);
            ej[j] = __builtin_amdgcn_readfirstlane(csr_eid[q]);
        }

        float4 hs[4];
        #pragma unroll
        for (int j = 0; j < 4; ++j)
            hs[j] = *(const float4*)&Hs[(size_t)sj[j] * HDIM + c0];

        const float* er0 = efeat + (size_t)ej[0] * EDIM;
        const float* er1 = efeat + (size_t)ej[1] * EDIM;
        const float* er2 = efeat + (size_t)ej[2] * EDIM;
        const float* er3 = efeat + (size_t)ej[3] * EDIM;

        float4 ev[4];
        #pragma unroll
        for (int j = 0; j < 4; ++j) ev[j] = make_float4(0.f, 0.f, 0.f, 0.f);

        #pragma unroll
        for (int k = 0; k < EDIM; ++k) {
            const float4 wv = *(const float4*)&w1c[k * HDIM + c0];
            const float f0 = er0[k], f1 = er1[k], f2 = er2[k], f3 = er3[k];
            ev[0].x = fmaf(f0, wv.x, ev[0].x); ev[0].y = fmaf(f0, wv.y, ev[0].y);
            ev[0].z = fmaf(f0, wv.z, ev[0].z); ev[0].w = fmaf(f0, wv.w, ev[0].w);
            ev[1].x = fmaf(f1, wv.x, ev[1].x); ev[1].y = fmaf(f1, wv.y, ev[1].y);
            ev[1].z = fmaf(f1, wv.z, ev[1].z); ev[1].w = fmaf(f1, wv.w, ev[1].w);
            ev[2].x = fmaf(f2, wv.x, ev[2].x); ev[2].y = fmaf(f2, wv.y, ev[2].y);
            ev[2].z = fmaf(f2, wv.z, ev[2].z); ev[2].w = fmaf(f2, wv.w, ev[2].w);
            ev[3].x = fmaf(f3, wv.x, ev[3].x); ev[3].y = fmaf(f3, wv.y, ev[3].y);
            ev[3].z = fmaf(f3, wv.z, ev[3].z); ev[3].w = fmaf(f3, wv.w, ev[3].w);
        }

        #pragma unroll
        for (int j = 0; j < 4; ++j) {
            if (j < nc) {
                acc.x += gelu_af(hs[j].x + hd.x + ev[j].x);
                acc.y += gelu_af(hs[j].y + hd.y + ev[j].y);
                acc.z += gelu_af(hs[j].z + hd.z + ev[j].z);
                acc.w += gelu_af(hs[j].w + hd.w + ev[j].w);
            }
        }
    }
    *(float4*)&Sagg[(size_t)d * HDIM + c0] = acc;
}

// ---------------- launcher ---------------------------------------------------
extern "C" void kernel_launch(void* const* d_in, const int* in_sizes, int n_in,
                              void* d_out, int out_size, void* d_ws, size_t ws_size,
                              hipStream_t stream)
{
    const float* nf    = (const float*)d_in[0];
    const int*   ei    = (const int*)  d_in[1];
    const float* efeat = (const float*)d_in[2];
    const float* inW   = (const float*)d_in[3];
    const float* inb   = (const float*)d_in[4];
    const float* mW1   = (const float*)d_in[5];
    const float* mb1   = (const float*)d_in[6];
    const float* mW2   = (const float*)d_in[7];
    const float* mb2   = (const float*)d_in[8];
    const float* uW1   = (const float*)d_in[9];
    const float* ub1   = (const float*)d_in[10];
    const float* uW2   = (const float*)d_in[11];
    const float* ub2   = (const float*)d_in[12];
    const float* outW  = (const float*)d_in[13];
    const float* outb  = (const float*)d_in[14];
    float* outp = (float*)d_out;

    char* p = (char*)d_ws;
    auto carve = [&](size_t bytes) -> void* {
        void* r = (void*)p;
        p += (bytes + 255) & ~(size_t)255;
        return r;
    };
    float* h   = (float*)carve((size_t)NN * HDIM * 4);
    float* T1  = (float*)carve((size_t)NN * HDIM * 4);
    float* T2  = (float*)carve((size_t)NN * HDIM * 4);
    float* T3  = (float*)carve((size_t)NN * HDIM * 4);
    int* csr_src = (int*)carve((size_t)NE * 4);
    int* csr_eid = (int*)carve((size_t)NE * 4);
    int* row_ptr = (int*)carve((size_t)(NN + 1) * 4);
    int* cursor  = (int*)carve((size_t)NN * 4);
    int* cnt     = (int*)carve((size_t)NN * 4);
    float* degf  = (float*)carve((size_t)NN * 4);
    unsigned short* wtbuf = (unsigned short*)carve((size_t)1638400 * 2);
    (void)ws_size; (void)in_sizes; (void)n_in; (void)out_size;

    const dim3 blk(256);
    const dim3 gN2(313, 2);
    const dim3 gN1(313, 1);

    tr_k<<<dim3(17, 8, 18), blk, 0, stream>>>(inW, mW1, mW2, uW1, uW2, outW, wtbuf);

    const unsigned short* wtIn  = wtbuf;
    const unsigned short* wtW1  = wtbuf + 16384;
    const unsigned short* wtW2  = wtbuf + 573440;
    const unsigned short* wtU1  = wtbuf + 835584;
    const unsigned short* wtU2  = wtbuf + 1359872;
    const unsigned short* wtOut = wtbuf + 1622016;

    for (int g = 0; g < NB; ++g) {
        const float* nf_g = nf    + (size_t)g * NN * NDIM;
        const int*   ei_g = ei    + (size_t)g * NE * 2;
        const float* ef_g = efeat + (size_t)g * NE * EDIM;
        float*      out_g = outp  + (size_t)g * NN * NDIM;

        hipMemsetAsync(cnt, 0, NN * sizeof(int), stream);
        hist_k<<<(NE + 255) / 256, blk, 0, stream>>>(ei_g, cnt);
        scan_k<<<1, blk, 0, stream>>>(cnt, row_ptr, cursor, degf);
        fill_k<<<(NE + 255) / 256, blk, 0, stream>>>(ei_g, cursor, csr_src, csr_eid);

        mgemm_k<0><<<gN2, blk, 0, stream>>>(nf_g, wtIn, NDIM, nullptr, nullptr, 0,
                                            inb, nullptr, h, NN, HDIM, NDIM, 0);

        for (int l = 0; l < NL; ++l) {
            const unsigned short* w1t = wtW1 + (size_t)l * 139264;
            const unsigned short* w2t = wtW2 + (size_t)l * 65536;
            const unsigned short* u1t = wtU1 + (size_t)l * 131072;
            const unsigned short* u2t = wtU2 + (size_t)l * 65536;
            const float* W1c = mW1 + (size_t)l * 544 * 256 + 512 * 256;

            mgemm_k<0><<<gN2, blk, 0, stream>>>(h, w1t, 544, nullptr, nullptr, 0,
                                                nullptr, nullptr, T1, NN, HDIM, HDIM, 0);
            mgemm_k<0><<<gN2, blk, 0, stream>>>(h, w1t + 256, 544, nullptr, nullptr, 0,
                                                mb1 + l * HDIM, nullptr, T2, NN, HDIM, HDIM, 0);
            edge_agg_k<<<NN / 4, blk, 0, stream>>>(T1, T2, ef_g, W1c,
                                                   csr_src, csr_eid, row_ptr, T3);
            mgemm_k<1><<<gN2, blk, 0, stream>>>(T3, w2t, HDIM, nullptr, nullptr, 0,
                                                mb2 + l * HDIM, degf, T1, NN, HDIM, HDIM, 0);
            mgemm_k<2><<<gN2, blk, 0, stream>>>(h, u1t, 512, T1, u1t + 256, 512,
                                                ub1 + l * HDIM, nullptr, T2, NN, HDIM, HDIM, HDIM);
            mgemm_k<3><<<gN2, blk, 0, stream>>>(T2, u2t, HDIM, nullptr, nullptr, 0,
                                                ub2 + l * HDIM, nullptr, h, NN, HDIM, HDIM, 0);
        }

        mgemm_k<0><<<gN1, blk, 0, stream>>>(h, wtOut, HDIM, nullptr, nullptr, 0,
                                            outb, nullptr, out_g, NN, NDIM, HDIM, 0);
    }
}

// Round 4
// 2372.648 us; speedup vs baseline: 1.7416x; 1.1048x over previous
//
#include <hip/hip_runtime.h>

#define NN 20000     // nodes per graph
#define NE 320000    // edges per graph
#define NB 2         // graphs
#define HDIM 256     // hidden
#define NDIM 64      // node feature dim
#define EDIM 32      // edge feature dim
#define NL 4         // layers

typedef short short8 __attribute__((ext_vector_type(8)));
typedef float f32x4 __attribute__((ext_vector_type(4)));

__device__ __forceinline__ float gelu_af(float x) {
    float u = 0.7978845608028654f * (x + 0.044715f * x * x * x);
    float e = __expf(2.0f * u);
    float t = 1.0f - 2.0f / (e + 1.0f);
    return 0.5f * x * (1.0f + t);
}

__device__ __forceinline__ unsigned short f2bf(float f) {
    unsigned int x = __float_as_uint(f);
    unsigned int r = (x + 0x7fffu + ((x >> 16) & 1u)) >> 16;
    return (unsigned short)r;
}
__device__ __forceinline__ float bf2f(unsigned short h) {
    return __uint_as_float(((unsigned int)h) << 16);
}

// ---------------- weight transpose + bf16 convert (once per launch) ---------
__global__ __launch_bounds__(256) void tr_k(
    const float* __restrict__ inW, const float* __restrict__ mW1,
    const float* __restrict__ mW2, const float* __restrict__ uW1,
    const float* __restrict__ uW2, const float* __restrict__ outW,
    unsigned short* __restrict__ dst)
{
    const int id = blockIdx.z;
    const float* src; int K, N; size_t doff;
    if (id == 0)       { src = inW;  K = 64;  N = 256; doff = 0; }
    else if (id <= 4)  { int l = id - 1;  src = mW1 + (size_t)l * 544 * 256; K = 544; N = 256; doff = 16384   + (size_t)l * 139264; }
    else if (id <= 8)  { int l = id - 5;  src = mW2 + (size_t)l * 256 * 256; K = 256; N = 256; doff = 573440  + (size_t)l * 65536;  }
    else if (id <= 12) { int l = id - 9;  src = uW1 + (size_t)l * 512 * 256; K = 512; N = 256; doff = 835584  + (size_t)l * 131072; }
    else if (id <= 16) { int l = id - 13; src = uW2 + (size_t)l * 256 * 256; K = 256; N = 256; doff = 1359872 + (size_t)l * 65536;  }
    else               { src = outW; K = 256; N = 64;  doff = 1622016; }

    const int k0 = blockIdx.x * 32, n0 = blockIdx.y * 32;
    if (k0 >= K || n0 >= N) return;   // block-uniform

    __shared__ float tile[32][33];
    const int tx = threadIdx.x & 31, ty = threadIdx.x >> 5;
    #pragma unroll
    for (int i = 0; i < 4; ++i) {
        int k = k0 + ty + i * 8, n = n0 + tx;
        tile[ty + i * 8][tx] = (k < K && n < N) ? src[(size_t)k * N + n] : 0.f;
    }
    __syncthreads();
    #pragma unroll
    for (int i = 0; i < 4; ++i) {
        int n = n0 + ty + i * 8, k = k0 + tx;
        if (n < N && k < K) dst[doff + (size_t)n * K + k] = f2bf(tile[tx][ty + i * 8]);
    }
}

// ---------------- MFMA GEMM (split-A hi/lo bf16, pre-transposed bf16 B) -----
// MODE 0: C = A@W + bias(optional)        MODE 1: C = A@W + degf[m]*bias
// MODE 2: C = gelu(A@W + A2@W2 + bias)    MODE 3: C = C + A@W + bias
template <int MODE>
__global__ __launch_bounds__(256) void mgemm_k(
    const float* __restrict__ A, const unsigned short* __restrict__ BT, int ldb,
    const float* __restrict__ A2, const unsigned short* __restrict__ BT2, int ldb2,
    const float* __restrict__ bias, const float* __restrict__ degf,
    float* __restrict__ C, int M, int N, int K, int K2)
{
    __shared__ unsigned char smem[64 * 80 * 2 + 128 * 80];  // ahi, alo, bt (80B-padded rows)
    unsigned char* ahi = smem;
    unsigned char* alo = smem + 64 * 80;
    unsigned char* btl = smem + 64 * 80 * 2;

    const int tid = threadIdx.x;
    const int bm = blockIdx.x * 64;
    const int bn = blockIdx.y * 128;
    const int w = tid >> 6, lane = tid & 63;
    const int wr = w >> 1, wc = w & 1;
    const int lrow = lane & 15, lg = lane >> 4;

    f32x4 acc[2][4];
    #pragma unroll
    for (int i = 0; i < 2; ++i)
        #pragma unroll
        for (int j = 0; j < 4; ++j) acc[i][j] = (f32x4){0.f, 0.f, 0.f, 0.f};

    const int t1 = K >> 5, t2 = K2 >> 5;
    for (int t = 0; t < t1 + t2; ++t) {
        const float* Ap; const unsigned short* Bp; int k0, lda, ldbv;
        if (t < t1) { Ap = A;  Bp = BT;  k0 = t * 32;        lda = K;  ldbv = ldb;  }
        else        { Ap = A2; Bp = BT2; k0 = (t - t1) * 32; lda = K2; ldbv = ldb2; }

        {   // stage A: 64 rows x 32 k, f32 -> hi/lo bf16
            const int row = tid >> 2, kq = (tid & 3) * 8;
            const int m = bm + row;
            float4 v0 = make_float4(0.f, 0.f, 0.f, 0.f), v1 = v0;
            if (m < M) {
                v0 = *(const float4*)&Ap[(size_t)m * lda + k0 + kq];
                v1 = *(const float4*)&Ap[(size_t)m * lda + k0 + kq + 4];
            }
            float vv[8] = {v0.x, v0.y, v0.z, v0.w, v1.x, v1.y, v1.z, v1.w};
            unsigned short hh[8], ll[8];
            #pragma unroll
            for (int j = 0; j < 8; ++j) {
                hh[j] = f2bf(vv[j]);
                ll[j] = f2bf(vv[j] - bf2f(hh[j]));
            }
            ushort4 ph0 = {hh[0], hh[1], hh[2], hh[3]}, ph1 = {hh[4], hh[5], hh[6], hh[7]};
            ushort4 pl0 = {ll[0], ll[1], ll[2], ll[3]}, pl1 = {ll[4], ll[5], ll[6], ll[7]};
            *(ushort4*)(ahi + row * 80 + kq * 2)     = ph0;
            *(ushort4*)(ahi + row * 80 + kq * 2 + 8) = ph1;
            *(ushort4*)(alo + row * 80 + kq * 2)     = pl0;
            *(ushort4*)(alo + row * 80 + kq * 2 + 8) = pl1;
        }
        {   // stage B: 128 n-rows x 32 k bf16
            const int row = tid >> 1, half = tid & 1;
            const int n = bn + row;
            #pragma unroll
            for (int c = 0; c < 2; ++c) {
                const int q = half * 2 + c;
                uint4 d = make_uint4(0u, 0u, 0u, 0u);
                if (n < N) d = *(const uint4*)&Bp[(size_t)n * ldbv + k0 + q * 8];
                *(uint4*)(btl + row * 80 + q * 16) = d;
            }
        }
        __syncthreads();

        short8 ah[2], al[2], bfr[4];
        #pragma unroll
        for (int mi = 0; mi < 2; ++mi) {
            const int r = wr * 32 + mi * 16 + lrow;
            ah[mi] = *(const short8*)(ahi + r * 80 + lg * 16);
            al[mi] = *(const short8*)(alo + r * 80 + lg * 16);
        }
        #pragma unroll
        for (int ni = 0; ni < 4; ++ni) {
            const int r = wc * 64 + ni * 16 + lrow;
            bfr[ni] = *(const short8*)(btl + r * 80 + lg * 16);
        }
        #pragma unroll
        for (int mi = 0; mi < 2; ++mi)
            #pragma unroll
            for (int ni = 0; ni < 4; ++ni) {
                acc[mi][ni] = __builtin_amdgcn_mfma_f32_16x16x32_bf16(ah[mi], bfr[ni], acc[mi][ni], 0, 0, 0);
                acc[mi][ni] = __builtin_amdgcn_mfma_f32_16x16x32_bf16(al[mi], bfr[ni], acc[mi][ni], 0, 0, 0);
            }
        __syncthreads();
    }

    // epilogue: D row = 4*lg + reg, col = lrow
    #pragma unroll
    for (int mi = 0; mi < 2; ++mi) {
        #pragma unroll
        for (int ni = 0; ni < 4; ++ni) {
            const int ncol = bn + wc * 64 + ni * 16 + lrow;
            if (ncol >= N) continue;
            const float bv = bias ? bias[ncol] : 0.f;
            const int mbase = bm + wr * 32 + mi * 16 + lg * 4;
            #pragma unroll
            for (int r = 0; r < 4; ++r) {
                const int m = mbase + r;
                if (m >= M) continue;
                float v = acc[mi][ni][r];
                if (MODE == 0)      v += bv;
                else if (MODE == 1) v += degf[m] * bv;
                else if (MODE == 2) v = gelu_af(v + bv);
                else                v += C[(size_t)m * N + ncol] + bv;
                C[(size_t)m * N + ncol] = v;
            }
        }
    }
}

// ---------------- Ef GEMM: Epos[p] = bf16( efeat[csr_eid[p]] @ W1c ) --------
// A gathered by csr_eid (rows in CSR position order), K=32 (single MFMA tile),
// B = W1c^T from wtW1 (k offset 512, ldb 544). Output bf16, row-major 256.
__global__ __launch_bounds__(256) void efgemm_k(
    const float* __restrict__ efeat, const int* __restrict__ csr_eid,
    const unsigned short* __restrict__ BT,   // wtW1 + 512 (n-major, ldb 544)
    unsigned short* __restrict__ Ef)
{
    __shared__ unsigned char smem[64 * 80 + 128 * 80];
    unsigned char* abuf = smem;
    unsigned char* btl  = smem + 64 * 80;

    const int tid = threadIdx.x;
    const int bm = blockIdx.x * 64;
    const int bn = blockIdx.y * 128;
    const int w = tid >> 6, lane = tid & 63;
    const int wr = w >> 1, wc = w & 1;
    const int lrow = lane & 15, lg = lane >> 4;

    {   // stage A: 64 gathered efeat rows -> bf16
        const int row = tid >> 2, kq = (tid & 3) * 8;
        const int eid = csr_eid[bm + row];
        float4 v0 = *(const float4*)&efeat[(size_t)eid * EDIM + kq];
        float4 v1 = *(const float4*)&efeat[(size_t)eid * EDIM + kq + 4];
        ushort4 p0 = {f2bf(v0.x), f2bf(v0.y), f2bf(v0.z), f2bf(v0.w)};
        ushort4 p1 = {f2bf(v1.x), f2bf(v1.y), f2bf(v1.z), f2bf(v1.w)};
        *(ushort4*)(abuf + row * 80 + kq * 2)     = p0;
        *(ushort4*)(abuf + row * 80 + kq * 2 + 8) = p1;
    }
    {   // stage B: 128 n-rows x 32 k bf16 (64B per row)
        const int row = tid >> 1, half = tid & 1;
        const int n = bn + row;
        #pragma unroll
        for (int c = 0; c < 2; ++c) {
            const int q = half * 2 + c;
            uint4 d = *(const uint4*)&BT[(size_t)n * 544 + q * 8];
            *(uint4*)(btl + row * 80 + q * 16) = d;
        }
    }
    __syncthreads();

    f32x4 acc[2][4];
    short8 av[2], bfr[4];
    #pragma unroll
    for (int mi = 0; mi < 2; ++mi)
        av[mi] = *(const short8*)(abuf + (wr * 32 + mi * 16 + lrow) * 80 + lg * 16);
    #pragma unroll
    for (int ni = 0; ni < 4; ++ni)
        bfr[ni] = *(const short8*)(btl + (wc * 64 + ni * 16 + lrow) * 80 + lg * 16);
    #pragma unroll
    for (int mi = 0; mi < 2; ++mi)
        #pragma unroll
        for (int ni = 0; ni < 4; ++ni) {
            acc[mi][ni] = (f32x4){0.f, 0.f, 0.f, 0.f};
            acc[mi][ni] = __builtin_amdgcn_mfma_f32_16x16x32_bf16(av[mi], bfr[ni], acc[mi][ni], 0, 0, 0);
        }

    #pragma unroll
    for (int mi = 0; mi < 2; ++mi)
        #pragma unroll
        for (int ni = 0; ni < 4; ++ni) {
            const int ncol = bn + wc * 64 + ni * 16 + lrow;
            const int mbase = bm + wr * 32 + mi * 16 + lg * 4;
            #pragma unroll
            for (int r = 0; r < 4; ++r)
                Ef[(size_t)(mbase + r) * HDIM + ncol] = f2bf(acc[mi][ni][r]);
        }
}

// ---------------- CSR build (counting sort by destination) -----------------
__global__ void hist_k(const int* __restrict__ ei, int* __restrict__ cnt) {
    int i = blockIdx.x * blockDim.x + threadIdx.x;
    if (i < NE) atomicAdd(&cnt[ei[2 * i + 1]], 1);
}

__global__ void scan_k(const int* __restrict__ cnt, int* __restrict__ row_ptr,
                       int* __restrict__ cursor, float* __restrict__ degf) {
    __shared__ int part[256];
    int tid = threadIdx.x;
    const int per = (NN + 255) >> 8;
    int s0 = tid * per;
    int s1 = s0 + per; if (s1 > NN) s1 = NN; if (s0 > NN) s0 = NN;
    int sum = 0;
    for (int i = s0; i < s1; ++i) sum += cnt[i];
    part[tid] = sum;
    __syncthreads();
    if (tid == 0) {
        int r = 0;
        for (int i = 0; i < 256; ++i) { int v = part[i]; part[i] = r; r += v; }
    }
    __syncthreads();
    int off = part[tid];
    for (int i = s0; i < s1; ++i) {
        int c = cnt[i];
        row_ptr[i] = off; cursor[i] = off; degf[i] = (float)c;
        off += c;
    }
    if (tid == 255) row_ptr[NN] = off;
}

__global__ void fill_k(const int* __restrict__ ei, int* __restrict__ cursor,
                       int* __restrict__ csr_src, int* __restrict__ csr_eid) {
    int i = blockIdx.x * blockDim.x + threadIdx.x;
    if (i < NE) {
        int s = ei[2 * i + 0];
        int d = ei[2 * i + 1];
        int pos = atomicAdd(&cursor[d], 1);
        csr_src[pos] = s;
        csr_eid[pos] = i;
    }
}

// ---------------- Edge aggregation v2 (Ef precomputed, CSR-ordered) ---------
// Sagg[d] = sum_{p in [row_ptr[d],row_ptr[d+1])} gelu(Hs[src_p] + Hd[d] + Ef[p])
// No LDS, no W1c; Ef reads are fully sequential bf16.
__global__ __launch_bounds__(256) void edge_agg2_k(
    const float* __restrict__ Hs, const float* __restrict__ Hdb,
    const unsigned short* __restrict__ Ef,
    const int* __restrict__ csr_src, const int* __restrict__ row_ptr,
    float* __restrict__ Sagg)
{
    const int tid = threadIdx.x;
    const int wave = tid >> 6, lane = tid & 63;
    const int d = blockIdx.x * 4 + wave;
    if (d >= NN) return;
    const int start = row_ptr[d], end = row_ptr[d + 1];
    const int c0 = lane * 4;

    const float4 hd = *(const float4*)&Hdb[(size_t)d * HDIM + c0];
    float4 acc = make_float4(0.f, 0.f, 0.f, 0.f);

    for (int p = start; p < end; p += 4) {
        const int nc = end - p;

        int sj[4];
        #pragma unroll
        for (int j = 0; j < 4; ++j) {
            int q = p + ((j < nc) ? j : 0);
            sj[j] = __builtin_amdgcn_readfirstlane(csr_src[q]);
        }

        float4 hs[4];
        ushort4 ef[4];
        #pragma unroll
        for (int j = 0; j < 4; ++j) {
            int q = p + ((j < nc) ? j : 0);
            hs[j] = *(const float4*)&Hs[(size_t)sj[j] * HDIM + c0];
            ef[j] = *(const ushort4*)&Ef[(size_t)q * HDIM + c0];
        }

        #pragma unroll
        for (int j = 0; j < 4; ++j) {
            if (j < nc) {   // wave-uniform predicate
                acc.x += gelu_af(hs[j].x + hd.x + bf2f(ef[j].x));
                acc.y += gelu_af(hs[j].y + hd.y + bf2f(ef[j].y));
                acc.z += gelu_af(hs[j].z + hd.z + bf2f(ef[j].z));
                acc.w += gelu_af(hs[j].w + hd.w + bf2f(ef[j].w));
            }
        }
    }
    *(float4*)&Sagg[(size_t)d * HDIM + c0] = acc;
}

// ---------------- Edge aggregation v1 (fallback if ws too small) ------------
__global__ __launch_bounds__(256) void edge_agg_k(
    const float* __restrict__ Hs, const float* __restrict__ Hdb,
    const float* __restrict__ efeat, const float* __restrict__ W1c,
    const int* __restrict__ csr_src, const int* __restrict__ csr_eid,
    const int* __restrict__ row_ptr, float* __restrict__ Sagg)
{
    __shared__ float w1c[EDIM * HDIM];
    const int tid = threadIdx.x;
    for (int i = tid; i < EDIM * HDIM / 4; i += 256)
        ((float4*)w1c)[i] = ((const float4*)W1c)[i];
    __syncthreads();

    const int wave = tid >> 6, lane = tid & 63;
    const int d = blockIdx.x * 4 + wave;
    if (d >= NN) return;
    const int start = row_ptr[d], end = row_ptr[d + 1];
    const int c0 = lane * 4;

    const float4 hd = *(const float4*)&Hdb[(size_t)d * HDIM + c0];
    float4 acc = make_float4(0.f, 0.f, 0.f, 0.f);

    for (int p = start; p < end; p += 4) {
        const int nc = end - p;
        int sj[4], ej[4];
        #pragma unroll
        for (int j = 0; j < 4; ++j) {
            int q = p + ((j < nc) ? j : 0);
            sj[j] = __builtin_amdgcn_readfirstlane(csr_src[q]);
            ej[j] = __builtin_amdgcn_readfirstlane(csr_eid[q]);
        }
        float4 hs[4];
        #pragma unroll
        for (int j = 0; j < 4; ++j)
            hs[j] = *(const float4*)&Hs[(size_t)sj[j] * HDIM + c0];
        const float* er0 = efeat + (size_t)ej[0] * EDIM;
        const float* er1 = efeat + (size_t)ej[1] * EDIM;
        const float* er2 = efeat + (size_t)ej[2] * EDIM;
        const float* er3 = efeat + (size_t)ej[3] * EDIM;
        float4 ev[4];
        #pragma unroll
        for (int j = 0; j < 4; ++j) ev[j] = make_float4(0.f, 0.f, 0.f, 0.f);
        #pragma unroll
        for (int k = 0; k < EDIM; ++k) {
            const float4 wv = *(const float4*)&w1c[k * HDIM + c0];
            const float f0 = er0[k], f1 = er1[k], f2 = er2[k], f3 = er3[k];
            ev[0].x = fmaf(f0, wv.x, ev[0].x); ev[0].y = fmaf(f0, wv.y, ev[0].y);
            ev[0].z = fmaf(f0, wv.z, ev[0].z); ev[0].w = fmaf(f0, wv.w, ev[0].w);
            ev[1].x = fmaf(f1, wv.x, ev[1].x); ev[1].y = fmaf(f1, wv.y, ev[1].y);
            ev[1].z = fmaf(f1, wv.z, ev[1].z); ev[1].w = fmaf(f1, wv.w, ev[1].w);
            ev[2].x = fmaf(f2, wv.x, ev[2].x); ev[2].y = fmaf(f2, wv.y, ev[2].y);
            ev[2].z = fmaf(f2, wv.z, ev[2].z); ev[2].w = fmaf(f2, wv.w, ev[2].w);
            ev[3].x = fmaf(f3, wv.x, ev[3].x); ev[3].y = fmaf(f3, wv.y, ev[3].y);
            ev[3].z = fmaf(f3, wv.z, ev[3].z); ev[3].w = fmaf(f3, wv.w, ev[3].w);
        }
        #pragma unroll
        for (int j = 0; j < 4; ++j) {
            if (j < nc) {
                acc.x += gelu_af(hs[j].x + hd.x + ev[j].x);
                acc.y += gelu_af(hs[j].y + hd.y + ev[j].y);
                acc.z += gelu_af(hs[j].z + hd.z + ev[j].z);
                acc.w += gelu_af(hs[j].w + hd.w + ev[j].w);
            }
        }
    }
    *(float4*)&Sagg[(size_t)d * HDIM + c0] = acc;
}

// ---------------- launcher ---------------------------------------------------
extern "C" void kernel_launch(void* const* d_in, const int* in_sizes, int n_in,
                              void* d_out, int out_size, void* d_ws, size_t ws_size,
                              hipStream_t stream)
{
    const float* nf    = (const float*)d_in[0];
    const int*   ei    = (const int*)  d_in[1];
    const float* efeat = (const float*)d_in[2];
    const float* inW   = (const float*)d_in[3];
    const float* inb   = (const float*)d_in[4];
    const float* mW1   = (const float*)d_in[5];
    const float* mb1   = (const float*)d_in[6];
    const float* mW2   = (const float*)d_in[7];
    const float* mb2   = (const float*)d_in[8];
    const float* uW1   = (const float*)d_in[9];
    const float* ub1   = (const float*)d_in[10];
    const float* uW2   = (const float*)d_in[11];
    const float* ub2   = (const float*)d_in[12];
    const float* outW  = (const float*)d_in[13];
    const float* outb  = (const float*)d_in[14];
    float* outp = (float*)d_out;

    char* p = (char*)d_ws;
    auto carve = [&](size_t bytes) -> void* {
        void* r = (void*)p;
        p += (bytes + 255) & ~(size_t)255;
        return r;
    };
    float* h   = (float*)carve((size_t)NN * HDIM * 4);
    float* T1  = (float*)carve((size_t)NN * HDIM * 4);
    float* T2  = (float*)carve((size_t)NN * HDIM * 4);
    float* T3  = (float*)carve((size_t)NN * HDIM * 4);
    int* csr_src = (int*)carve((size_t)NE * 4);
    int* csr_eid = (int*)carve((size_t)NE * 4);
    int* row_ptr = (int*)carve((size_t)(NN + 1) * 4);
    int* cursor  = (int*)carve((size_t)NN * 4);
    int* cnt     = (int*)carve((size_t)NN * 4);
    float* degf  = (float*)carve((size_t)NN * 4);
    unsigned short* wtbuf = (unsigned short*)carve((size_t)1638400 * 2);
    unsigned short* Epos  = (unsigned short*)carve((size_t)NE * HDIM * 2);  // 164 MB
    const bool useEf = ((size_t)(p - (char*)d_ws) <= ws_size);
    (void)in_sizes; (void)n_in; (void)out_size;

    const dim3 blk(256);
    const dim3 gN2(313, 2);
    const dim3 gN1(313, 1);
    const dim3 gEf(NE / 64, 2);

    tr_k<<<dim3(17, 8, 18), blk, 0, stream>>>(inW, mW1, mW2, uW1, uW2, outW, wtbuf);

    const unsigned short* wtIn  = wtbuf;
    const unsigned short* wtW1  = wtbuf + 16384;
    const unsigned short* wtW2  = wtbuf + 573440;
    const unsigned short* wtU1  = wtbuf + 835584;
    const unsigned short* wtU2  = wtbuf + 1359872;
    const unsigned short* wtOut = wtbuf + 1622016;

    for (int g = 0; g < NB; ++g) {
        const float* nf_g = nf    + (size_t)g * NN * NDIM;
        const int*   ei_g = ei    + (size_t)g * NE * 2;
        const float* ef_g = efeat + (size_t)g * NE * EDIM;
        float*      out_g = outp  + (size_t)g * NN * NDIM;

        hipMemsetAsync(cnt, 0, NN * sizeof(int), stream);
        hist_k<<<(NE + 255) / 256, blk, 0, stream>>>(ei_g, cnt);
        scan_k<<<1, blk, 0, stream>>>(cnt, row_ptr, cursor, degf);
        fill_k<<<(NE + 255) / 256, blk, 0, stream>>>(ei_g, cursor, csr_src, csr_eid);

        mgemm_k<0><<<gN2, blk, 0, stream>>>(nf_g, wtIn, NDIM, nullptr, nullptr, 0,
                                            inb, nullptr, h, NN, HDIM, NDIM, 0);

        for (int l = 0; l < NL; ++l) {
            const unsigned short* w1t = wtW1 + (size_t)l * 139264;
            const unsigned short* w2t = wtW2 + (size_t)l * 65536;
            const unsigned short* u1t = wtU1 + (size_t)l * 131072;
            const unsigned short* u2t = wtU2 + (size_t)l * 65536;
            const float* W1c = mW1 + (size_t)l * 544 * 256 + 512 * 256;

            // Hs = h @ W1[0:256]  (T1);  Hd = h @ W1[256:512] + b1  (T2)
            mgemm_k<0><<<gN2, blk, 0, stream>>>(h, w1t, 544, nullptr, nullptr, 0,
                                                nullptr, nullptr, T1, NN, HDIM, HDIM, 0);
            mgemm_k<0><<<gN2, blk, 0, stream>>>(h, w1t + 256, 544, nullptr, nullptr, 0,
                                                mb1 + l * HDIM, nullptr, T2, NN, HDIM, HDIM, 0);
            if (useEf) {
                // Epos[p] = bf16(efeat[csr_eid[p]] @ W1c), CSR order
                efgemm_k<<<gEf, blk, 0, stream>>>(ef_g, csr_eid, w1t + 512, Epos);
                edge_agg2_k<<<NN / 4, blk, 0, stream>>>(T1, T2, Epos,
                                                        csr_src, row_ptr, T3);
            } else {
                edge_agg_k<<<NN / 4, blk, 0, stream>>>(T1, T2, ef_g, W1c,
                                                       csr_src, csr_eid, row_ptr, T3);
            }
            // agg = Sagg @ W2 + deg*b2      (T1)
            mgemm_k<1><<<gN2, blk, 0, stream>>>(T3, w2t, HDIM, nullptr, nullptr, 0,
                                                mb2 + l * HDIM, degf, T1, NN, HDIM, HDIM, 0);
            // U = gelu(h@V1a + agg@V1b + c1) (T2)
            mgemm_k<2><<<gN2, blk, 0, stream>>>(h, u1t, 512, T1, u1t + 256, 512,
                                                ub1 + l * HDIM, nullptr, T2, NN, HDIM, HDIM, HDIM);
            // h += U @ V2 + c2
            mgemm_k<3><<<gN2, blk, 0, stream>>>(T2, u2t, HDIM, nullptr, nullptr, 0,
                                                ub2 + l * HDIM, nullptr, h, NN, HDIM, HDIM, 0);
        }

        mgemm_k<0><<<gN1, blk, 0, stream>>>(h, wtOut, HDIM, nullptr, nullptr, 0,
                                            outb, nullptr, out_g, NN, NDIM, HDIM, 0);
    }
}

// Round 5
// 2157.381 us; speedup vs baseline: 1.9153x; 1.0998x over previous
//
#include <hip/hip_runtime.h>

#define NN 20000     // nodes per graph
#define NE 320000    // edges per graph
#define NB 2         // graphs
#define HDIM 256     // hidden
#define NDIM 64      // node feature dim
#define EDIM 32      // edge feature dim
#define NL 4         // layers

typedef short short8 __attribute__((ext_vector_type(8)));
typedef float f32x4 __attribute__((ext_vector_type(4)));

__device__ __forceinline__ float gelu_af(float x) {
    float u = 0.7978845608028654f * (x + 0.044715f * x * x * x);
    float e = __expf(2.0f * u);
    float t = 1.0f - 2.0f / (e + 1.0f);
    return 0.5f * x * (1.0f + t);
}

__device__ __forceinline__ unsigned short f2bf(float f) {
    unsigned int x = __float_as_uint(f);
    unsigned int r = (x + 0x7fffu + ((x >> 16) & 1u)) >> 16;
    return (unsigned short)r;
}
__device__ __forceinline__ float bf2f(unsigned short h) {
    return __uint_as_float(((unsigned int)h) << 16);
}

// ---------------- weight transpose + bf16 convert (once per launch) ---------
__global__ __launch_bounds__(256) void tr_k(
    const float* __restrict__ inW, const float* __restrict__ mW1,
    const float* __restrict__ mW2, const float* __restrict__ uW1,
    const float* __restrict__ uW2, const float* __restrict__ outW,
    unsigned short* __restrict__ dst)
{
    const int id = blockIdx.z;
    const float* src; int K, N; size_t doff;
    if (id == 0)       { src = inW;  K = 64;  N = 256; doff = 0; }
    else if (id <= 4)  { int l = id - 1;  src = mW1 + (size_t)l * 544 * 256; K = 544; N = 256; doff = 16384   + (size_t)l * 139264; }
    else if (id <= 8)  { int l = id - 5;  src = mW2 + (size_t)l * 256 * 256; K = 256; N = 256; doff = 573440  + (size_t)l * 65536;  }
    else if (id <= 12) { int l = id - 9;  src = uW1 + (size_t)l * 512 * 256; K = 512; N = 256; doff = 835584  + (size_t)l * 131072; }
    else if (id <= 16) { int l = id - 13; src = uW2 + (size_t)l * 256 * 256; K = 256; N = 256; doff = 1359872 + (size_t)l * 65536;  }
    else               { src = outW; K = 256; N = 64;  doff = 1622016; }

    const int k0 = blockIdx.x * 32, n0 = blockIdx.y * 32;
    if (k0 >= K || n0 >= N) return;   // block-uniform

    __shared__ float tile[32][33];
    const int tx = threadIdx.x & 31, ty = threadIdx.x >> 5;
    #pragma unroll
    for (int i = 0; i < 4; ++i) {
        int k = k0 + ty + i * 8, n = n0 + tx;
        tile[ty + i * 8][tx] = (k < K && n < N) ? src[(size_t)k * N + n] : 0.f;
    }
    __syncthreads();
    #pragma unroll
    for (int i = 0; i < 4; ++i) {
        int n = n0 + ty + i * 8, k = k0 + tx;
        if (n < N && k < K) dst[doff + (size_t)n * K + k] = f2bf(tile[tx][ty + i * 8]);
    }
}

// ---------------- W2@V1b precompute: WT[n][k] = sum_j W2[k][j] V1b[j][n] ----
__global__ __launch_bounds__(256) void wv_k(
    const float* __restrict__ mW2, const float* __restrict__ uW1,
    unsigned short* __restrict__ w2v1bT)
{
    const int l = blockIdx.z;
    const float* W2  = mW2 + (size_t)l * 65536;
    const float* V1b = uW1 + (size_t)l * 131072 + 65536;   // rows 256.. of [512][256]
    const int n0 = blockIdx.x * 16, k0 = blockIdx.y * 16;
    const int tx = threadIdx.x & 15, ty = threadIdx.x >> 4;
    __shared__ float sW[16][17], sV[16][17];
    float acc = 0.f;
    for (int j0 = 0; j0 < 256; j0 += 16) {
        sW[ty][tx] = W2[(size_t)(k0 + ty) * 256 + j0 + tx];
        sV[ty][tx] = V1b[(size_t)(j0 + ty) * 256 + n0 + tx];
        __syncthreads();
        #pragma unroll
        for (int jj = 0; jj < 16; ++jj)
            acc = fmaf(sW[ty][jj], sV[jj][tx], acc);
        __syncthreads();
    }
    w2v1bT[(size_t)l * 65536 + (size_t)(n0 + tx) * 256 + (k0 + ty)] = f2bf(acc);
}

// ---------------- b2@V1b + fused bias512 build ------------------------------
__global__ void bv_k(const float* __restrict__ mb1, const float* __restrict__ mb2,
                     const float* __restrict__ uW1,
                     float* __restrict__ b2v, float* __restrict__ bias512)
{
    const int l = blockIdx.x, t = threadIdx.x;   // 512 threads
    if (t < 256) {
        const float* V1b = uW1 + (size_t)l * 131072 + 65536;
        const float* b2  = mb2 + l * 256;
        float s = 0.f;
        for (int j = 0; j < 256; ++j) s = fmaf(b2[j], V1b[(size_t)j * 256 + t], s);
        b2v[l * 256 + t] = s;
    }
    bias512[l * 512 + t] = (t < 256) ? 0.f : mb1[l * 256 + (t - 256)];
}

// ---------------- MFMA GEMM ------------------------------------------------
// ASPLIT=0: A is f32, runtime hi/lo split.  ASPLIT=1: A (and A2) pre-split planes.
// CSPLIT=0: C f32.  CSPLIT=1: C hi/lo bf16 planes (Ch/Cl).
// MODE 0: C = A@W + bias(optional)
// MODE 3: C = (Chi+Clo) + A@W + bias      (residual; A != C buffers)
// MODE 4: C = gelu(A@W + A2@W2 + degf[m]*bias2 + bias)
template <int MODE, int ASPLIT, int CSPLIT>
__global__ __launch_bounds__(256) void mgemm_k(
    const float* __restrict__ A,
    const unsigned short* __restrict__ Ah, const unsigned short* __restrict__ Al,
    const unsigned short* __restrict__ BT, int ldb,
    const unsigned short* __restrict__ A2h, const unsigned short* __restrict__ A2l,
    const unsigned short* __restrict__ BT2, int ldb2,
    const float* __restrict__ bias, const float* __restrict__ bias2,
    const float* __restrict__ degf,
    float* __restrict__ C, unsigned short* __restrict__ Ch, unsigned short* __restrict__ Cl,
    int M, int N, int K, int K2, int bkoff)
{
    __shared__ unsigned char smem[64 * 80 * 2 + 128 * 80];  // ahi, alo, bt (80B rows)
    unsigned char* ahi = smem;
    unsigned char* alo = smem + 64 * 80;
    unsigned char* btl = smem + 64 * 80 * 2;

    const int tid = threadIdx.x;
    const int bm = blockIdx.x * 64;
    const int bn = blockIdx.y * 128;
    const int w = tid >> 6, lane = tid & 63;
    const int wr = w >> 1, wc = w & 1;
    const int lrow = lane & 15, lg = lane >> 4;

    f32x4 acc[2][4];
    #pragma unroll
    for (int i = 0; i < 2; ++i)
        #pragma unroll
        for (int j = 0; j < 4; ++j) acc[i][j] = (f32x4){0.f, 0.f, 0.f, 0.f};

    const int t1 = K >> 5, t2 = K2 >> 5;
    for (int t = 0; t < t1 + t2; ++t) {
        int k0, lda, ldbv;
        const float* Ap; const unsigned short* Ahp; const unsigned short* Alp;
        const unsigned short* Bp;
        if (t < t1) { Ap = A;  Ahp = Ah;  Alp = Al;  Bp = BT;  k0 = t * 32;        lda = K;  ldbv = ldb;  }
        else        { Ap = nullptr; Ahp = A2h; Alp = A2l; Bp = BT2; k0 = (t - t1) * 32; lda = K2; ldbv = ldb2; }

        {   // stage A
            const int row = tid >> 2, kq = (tid & 3) * 8;
            const int m = bm + row;
            if (ASPLIT) {
                uint4 hv = make_uint4(0u, 0u, 0u, 0u), lv = hv;
                if (m < M) {
                    hv = *(const uint4*)&Ahp[(size_t)m * lda + k0 + kq];
                    lv = *(const uint4*)&Alp[(size_t)m * lda + k0 + kq];
                }
                *(uint4*)(ahi + row * 80 + kq * 2) = hv;
                *(uint4*)(alo + row * 80 + kq * 2) = lv;
            } else {
                float4 v0 = make_float4(0.f, 0.f, 0.f, 0.f), v1 = v0;
                if (m < M) {
                    v0 = *(const float4*)&Ap[(size_t)m * lda + k0 + kq];
                    v1 = *(const float4*)&Ap[(size_t)m * lda + k0 + kq + 4];
                }
                float vv[8] = {v0.x, v0.y, v0.z, v0.w, v1.x, v1.y, v1.z, v1.w};
                unsigned short hh[8], ll[8];
                #pragma unroll
                for (int j = 0; j < 8; ++j) {
                    hh[j] = f2bf(vv[j]);
                    ll[j] = f2bf(vv[j] - bf2f(hh[j]));
                }
                ushort4 ph0 = {hh[0], hh[1], hh[2], hh[3]}, ph1 = {hh[4], hh[5], hh[6], hh[7]};
                ushort4 pl0 = {ll[0], ll[1], ll[2], ll[3]}, pl1 = {ll[4], ll[5], ll[6], ll[7]};
                *(ushort4*)(ahi + row * 80 + kq * 2)     = ph0;
                *(ushort4*)(ahi + row * 80 + kq * 2 + 8) = ph1;
                *(ushort4*)(alo + row * 80 + kq * 2)     = pl0;
                *(ushort4*)(alo + row * 80 + kq * 2 + 8) = pl1;
            }
        }
        {   // stage B: 128 n-rows x 32 k bf16; fused-B via (n>>8)*bkoff column shift
            const int row = tid >> 1, half = tid & 1;
            const int n = bn + row;
            const unsigned short* brow = Bp + (size_t)(n & 255) * ldbv + (n >> 8) * bkoff;
            #pragma unroll
            for (int c = 0; c < 2; ++c) {
                const int q = half * 2 + c;
                uint4 d = make_uint4(0u, 0u, 0u, 0u);
                if (n < N) d = *(const uint4*)&brow[k0 + q * 8];
                *(uint4*)(btl + row * 80 + q * 16) = d;
            }
        }
        __syncthreads();

        short8 ah[2], al[2], bfr[4];
        #pragma unroll
        for (int mi = 0; mi < 2; ++mi) {
            const int r = wr * 32 + mi * 16 + lrow;
            ah[mi] = *(const short8*)(ahi + r * 80 + lg * 16);
            al[mi] = *(const short8*)(alo + r * 80 + lg * 16);
        }
        #pragma unroll
        for (int ni = 0; ni < 4; ++ni) {
            const int r = wc * 64 + ni * 16 + lrow;
            bfr[ni] = *(const short8*)(btl + r * 80 + lg * 16);
        }
        #pragma unroll
        for (int mi = 0; mi < 2; ++mi)
            #pragma unroll
            for (int ni = 0; ni < 4; ++ni) {
                acc[mi][ni] = __builtin_amdgcn_mfma_f32_16x16x32_bf16(ah[mi], bfr[ni], acc[mi][ni], 0, 0, 0);
                acc[mi][ni] = __builtin_amdgcn_mfma_f32_16x16x32_bf16(al[mi], bfr[ni], acc[mi][ni], 0, 0, 0);
            }
        __syncthreads();
    }

    // epilogue: D row = 4*lg + reg, col = lrow
    #pragma unroll
    for (int mi = 0; mi < 2; ++mi) {
        #pragma unroll
        for (int ni = 0; ni < 4; ++ni) {
            const int ncol = bn + wc * 64 + ni * 16 + lrow;
            if (ncol >= N) continue;
            const float bv = bias ? bias[ncol] : 0.f;
            const float b2vv = (MODE == 4) ? bias2[ncol] : 0.f;
            const int mbase = bm + wr * 32 + mi * 16 + lg * 4;
            #pragma unroll
            for (int r = 0; r < 4; ++r) {
                const int m = mbase + r;
                if (m >= M) continue;
                const size_t cb = (size_t)m * N + ncol;
                float v = acc[mi][ni][r];
                if (MODE == 0)      v += bv;
                else if (MODE == 3) v += bf2f(Ch[cb]) + bf2f(Cl[cb]) + bv;
                else                v = gelu_af(v + degf[m] * b2vv + bv);
                if (CSPLIT) {
                    unsigned short hi = f2bf(v);
                    unsigned short lo = f2bf(v - bf2f(hi));
                    Ch[cb] = hi; Cl[cb] = lo;
                } else {
                    C[cb] = v;
                }
            }
        }
    }
}

// ---------------- Ef GEMM: Epos[p] = bf16( efeat[csr_eid[p]] @ W1c ) --------
__global__ __launch_bounds__(256) void efgemm_k(
    const float* __restrict__ efeat, const int* __restrict__ csr_eid,
    const unsigned short* __restrict__ BT,   // wtW1 + 512 (n-major, ldb 544)
    unsigned short* __restrict__ Ef)
{
    __shared__ unsigned char smem[64 * 80 + 128 * 80];
    unsigned char* abuf = smem;
    unsigned char* btl  = smem + 64 * 80;

    const int tid = threadIdx.x;
    const int bm = blockIdx.x * 64;
    const int bn = blockIdx.y * 128;
    const int w = tid >> 6, lane = tid & 63;
    const int wr = w >> 1, wc = w & 1;
    const int lrow = lane & 15, lg = lane >> 4;

    {   // stage A: 64 gathered efeat rows -> bf16
        const int row = tid >> 2, kq = (tid & 3) * 8;
        const int eid = csr_eid[bm + row];
        float4 v0 = *(const float4*)&efeat[(size_t)eid * EDIM + kq];
        float4 v1 = *(const float4*)&efeat[(size_t)eid * EDIM + kq + 4];
        ushort4 p0 = {f2bf(v0.x), f2bf(v0.y), f2bf(v0.z), f2bf(v0.w)};
        ushort4 p1 = {f2bf(v1.x), f2bf(v1.y), f2bf(v1.z), f2bf(v1.w)};
        *(ushort4*)(abuf + row * 80 + kq * 2)     = p0;
        *(ushort4*)(abuf + row * 80 + kq * 2 + 8) = p1;
    }
    {   // stage B
        const int row = tid >> 1, half = tid & 1;
        const int n = bn + row;
        #pragma unroll
        for (int c = 0; c < 2; ++c) {
            const int q = half * 2 + c;
            uint4 d = *(const uint4*)&BT[(size_t)n * 544 + q * 8];
            *(uint4*)(btl + row * 80 + q * 16) = d;
        }
    }
    __syncthreads();

    f32x4 acc[2][4];
    short8 av[2], bfr[4];
    #pragma unroll
    for (int mi = 0; mi < 2; ++mi)
        av[mi] = *(const short8*)(abuf + (wr * 32 + mi * 16 + lrow) * 80 + lg * 16);
    #pragma unroll
    for (int ni = 0; ni < 4; ++ni)
        bfr[ni] = *(const short8*)(btl + (wc * 64 + ni * 16 + lrow) * 80 + lg * 16);
    #pragma unroll
    for (int mi = 0; mi < 2; ++mi)
        #pragma unroll
        for (int ni = 0; ni < 4; ++ni) {
            acc[mi][ni] = (f32x4){0.f, 0.f, 0.f, 0.f};
            acc[mi][ni] = __builtin_amdgcn_mfma_f32_16x16x32_bf16(av[mi], bfr[ni], acc[mi][ni], 0, 0, 0);
        }

    #pragma unroll
    for (int mi = 0; mi < 2; ++mi)
        #pragma unroll
        for (int ni = 0; ni < 4; ++ni) {
            const int ncol = bn + wc * 64 + ni * 16 + lrow;
            const int mbase = bm + wr * 32 + mi * 16 + lg * 4;
            #pragma unroll
            for (int r = 0; r < 4; ++r)
                Ef[(size_t)(mbase + r) * HDIM + ncol] = f2bf(acc[mi][ni][r]);
        }
}

// ---------------- CSR build (counting sort by destination) -----------------
__global__ void hist_k(const int* __restrict__ ei, int* __restrict__ cnt) {
    int i = blockIdx.x * blockDim.x + threadIdx.x;
    if (i < NE) atomicAdd(&cnt[ei[2 * i + 1]], 1);
}

__global__ void scan_k(const int* __restrict__ cnt, int* __restrict__ row_ptr,
                       int* __restrict__ cursor, float* __restrict__ degf) {
    __shared__ int part[256];
    int tid = threadIdx.x;
    const int per = (NN + 255) >> 8;
    int s0 = tid * per;
    int s1 = s0 + per; if (s1 > NN) s1 = NN; if (s0 > NN) s0 = NN;
    int sum = 0;
    for (int i = s0; i < s1; ++i) sum += cnt[i];
    part[tid] = sum;
    __syncthreads();
    if (tid == 0) {
        int r = 0;
        for (int i = 0; i < 256; ++i) { int v = part[i]; part[i] = r; r += v; }
    }
    __syncthreads();
    int off = part[tid];
    for (int i = s0; i < s1; ++i) {
        int c = cnt[i];
        row_ptr[i] = off; cursor[i] = off; degf[i] = (float)c;
        off += c;
    }
    if (tid == 255) row_ptr[NN] = off;
}

__global__ void fill_k(const int* __restrict__ ei, int* __restrict__ cursor,
                       int* __restrict__ csr_src, int* __restrict__ csr_eid) {
    int i = blockIdx.x * blockDim.x + threadIdx.x;
    if (i < NE) {
        int s = ei[2 * i + 0];
        int d = ei[2 * i + 1];
        int pos = atomicAdd(&cursor[d], 1);
        csr_src[pos] = s;
        csr_eid[pos] = i;
    }
}

// ---------------- Edge aggregation (T12 fused Hs|Hd, Ef CSR-ordered) --------
// Sagg[d] = sum_p gelu(T12[src_p][0:256] + T12[d][256:512] + Ef[p]) -> split bf16
__global__ __launch_bounds__(256) void edge_agg2_k(
    const float* __restrict__ T12, const unsigned short* __restrict__ Ef,
    const int* __restrict__ csr_src, const int* __restrict__ row_ptr,
    unsigned short* __restrict__ Shi, unsigned short* __restrict__ Slo)
{
    const int tid = threadIdx.x;
    const int wave = tid >> 6, lane = tid & 63;
    const int d = blockIdx.x * 4 + wave;
    if (d >= NN) return;
    const int start = row_ptr[d], end = row_ptr[d + 1];
    const int c0 = lane * 4;

    const float4 hd = *(const float4*)&T12[(size_t)d * 512 + 256 + c0];
    float4 acc = make_float4(0.f, 0.f, 0.f, 0.f);

    for (int p = start; p < end; p += 4) {
        const int nc = end - p;

        int sj[4];
        #pragma unroll
        for (int j = 0; j < 4; ++j) {
            int q = p + ((j < nc) ? j : 0);
            sj[j] = __builtin_amdgcn_readfirstlane(csr_src[q]);
        }

        float4 hs[4];
        ushort4 ef[4];
        #pragma unroll
        for (int j = 0; j < 4; ++j) {
            int q = p + ((j < nc) ? j : 0);
            hs[j] = *(const float4*)&T12[(size_t)sj[j] * 512 + c0];
            ef[j] = *(const ushort4*)&Ef[(size_t)q * HDIM + c0];
        }

        #pragma unroll
        for (int j = 0; j < 4; ++j) {
            if (j < nc) {   // wave-uniform predicate
                acc.x += gelu_af(hs[j].x + hd.x + bf2f(ef[j].x));
                acc.y += gelu_af(hs[j].y + hd.y + bf2f(ef[j].y));
                acc.z += gelu_af(hs[j].z + hd.z + bf2f(ef[j].z));
                acc.w += gelu_af(hs[j].w + hd.w + bf2f(ef[j].w));
            }
        }
    }
    ushort4 ho, lo;
    ho.x = f2bf(acc.x); lo.x = f2bf(acc.x - bf2f(ho.x));
    ho.y = f2bf(acc.y); lo.y = f2bf(acc.y - bf2f(ho.y));
    ho.z = f2bf(acc.z); lo.z = f2bf(acc.z - bf2f(ho.z));
    ho.w = f2bf(acc.w); lo.w = f2bf(acc.w - bf2f(ho.w));
    *(ushort4*)&Shi[(size_t)d * HDIM + c0] = ho;
    *(ushort4*)&Slo[(size_t)d * HDIM + c0] = lo;
}

// ---------------- launcher ---------------------------------------------------
extern "C" void kernel_launch(void* const* d_in, const int* in_sizes, int n_in,
                              void* d_out, int out_size, void* d_ws, size_t ws_size,
                              hipStream_t stream)
{
    const float* nf    = (const float*)d_in[0];
    const int*   ei    = (const int*)  d_in[1];
    const float* efeat = (const float*)d_in[2];
    const float* inW   = (const float*)d_in[3];
    const float* inb   = (const float*)d_in[4];
    const float* mW1   = (const float*)d_in[5];
    const float* mb1   = (const float*)d_in[6];
    const float* mW2   = (const float*)d_in[7];
    const float* mb2   = (const float*)d_in[8];
    const float* uW1   = (const float*)d_in[9];
    const float* ub1   = (const float*)d_in[10];
    const float* uW2   = (const float*)d_in[11];
    const float* ub2   = (const float*)d_in[12];
    const float* outW  = (const float*)d_in[13];
    const float* outb  = (const float*)d_in[14];
    float* outp = (float*)d_out;

    char* p = (char*)d_ws;
    auto carve = [&](size_t bytes) -> void* {
        void* r = (void*)p;
        p += (bytes + 255) & ~(size_t)255;
        return r;
    };
    // activations: hi/lo bf16 planes (plane stride NN*HDIM elems)
    unsigned short* hS  = (unsigned short*)carve((size_t)2 * NN * HDIM * 2);
    unsigned short* T3S = (unsigned short*)carve((size_t)2 * NN * HDIM * 2);
    float* T12 = (float*)carve((size_t)NN * 512 * 4);      // Hs|Hd fused, f32
    unsigned short* US = (unsigned short*)T12;             // alias: U planes reuse dead T12
    int* csr_src = (int*)carve((size_t)NE * 4);
    int* csr_eid = (int*)carve((size_t)NE * 4);
    int* row_ptr = (int*)carve((size_t)(NN + 1) * 4);
    int* cursor  = (int*)carve((size_t)NN * 4);
    int* cnt     = (int*)carve((size_t)NN * 4);
    float* degf  = (float*)carve((size_t)NN * 4);
    unsigned short* wtbuf  = (unsigned short*)carve((size_t)1638400 * 2);
    unsigned short* w2v1bT = (unsigned short*)carve((size_t)4 * 65536 * 2);
    float* b2v     = (float*)carve((size_t)4 * 256 * 4);
    float* bias512 = (float*)carve((size_t)4 * 512 * 4);
    unsigned short* Epos = (unsigned short*)carve((size_t)NE * HDIM * 2);  // 164 MB
    (void)ws_size; (void)in_sizes; (void)n_in; (void)out_size;

    unsigned short* hHi  = hS;   unsigned short* hLo  = hS  + (size_t)NN * HDIM;
    unsigned short* t3Hi = T3S;  unsigned short* t3Lo = T3S + (size_t)NN * HDIM;
    unsigned short* uHi  = US;   unsigned short* uLo  = US  + (size_t)NN * HDIM;

    const dim3 blk(256);
    const dim3 gIn(313, 2), gHsHd(313, 4), gU(313, 2), gRes(313, 2), gOut(313, 1);
    const dim3 gEf(NE / 64, 2);

    // once: weight transforms
    tr_k<<<dim3(17, 8, 18), blk, 0, stream>>>(inW, mW1, mW2, uW1, uW2, outW, wtbuf);
    wv_k<<<dim3(16, 16, 4), blk, 0, stream>>>(mW2, uW1, w2v1bT);
    bv_k<<<dim3(4), dim3(512), 0, stream>>>(mb1, mb2, uW1, b2v, bias512);

    const unsigned short* wtIn  = wtbuf;
    const unsigned short* wtW1  = wtbuf + 16384;
    const unsigned short* wtU1  = wtbuf + 835584;
    const unsigned short* wtU2  = wtbuf + 1359872;
    const unsigned short* wtOut = wtbuf + 1622016;

    for (int g = 0; g < NB; ++g) {
        const float* nf_g = nf    + (size_t)g * NN * NDIM;
        const int*   ei_g = ei    + (size_t)g * NE * 2;
        const float* ef_g = efeat + (size_t)g * NE * EDIM;
        float*      out_g = outp  + (size_t)g * NN * NDIM;

        hipMemsetAsync(cnt, 0, NN * sizeof(int), stream);
        hist_k<<<(NE + 255) / 256, blk, 0, stream>>>(ei_g, cnt);
        scan_k<<<1, blk, 0, stream>>>(cnt, row_ptr, cursor, degf);
        fill_k<<<(NE + 255) / 256, blk, 0, stream>>>(ei_g, cursor, csr_src, csr_eid);

        // h = nf @ in_W + in_b  -> split planes
        mgemm_k<0, 0, 1><<<gIn, blk, 0, stream>>>(
            nf_g, nullptr, nullptr, wtIn, NDIM,
            nullptr, nullptr, nullptr, 0,
            inb, nullptr, nullptr,
            nullptr, hHi, hLo, NN, HDIM, NDIM, 0, 0);

        for (int l = 0; l < NL; ++l) {
            const unsigned short* w1t = wtW1 + (size_t)l * 139264;
            const unsigned short* u1t = wtU1 + (size_t)l * 131072;
            const unsigned short* u2t = wtU2 + (size_t)l * 65536;

            // T12 = h @ [W1a|W1b] + [0,b1]   (fused N=512)
            mgemm_k<0, 1, 0><<<gHsHd, blk, 0, stream>>>(
                nullptr, hHi, hLo, w1t, 544,
                nullptr, nullptr, nullptr, 0,
                bias512 + l * 512, nullptr, nullptr,
                T12, nullptr, nullptr, NN, 512, HDIM, 0, 256);

            // Epos[p] = bf16(efeat[csr_eid[p]] @ W1c)
            efgemm_k<<<gEf, blk, 0, stream>>>(ef_g, csr_eid, w1t + 512, Epos);

            // Sagg -> T3 split planes
            edge_agg2_k<<<NN / 4, blk, 0, stream>>>(T12, Epos, csr_src, row_ptr,
                                                    t3Hi, t3Lo);

            // U = gelu(h@V1a + Sagg@(W2@V1b) + deg*(b2@V1b) + c1) -> US (aliases T12)
            mgemm_k<4, 1, 1><<<gU, blk, 0, stream>>>(
                nullptr, hHi, hLo, u1t, 512,
                t3Hi, t3Lo, w2v1bT + (size_t)l * 65536, 256,
                ub1 + l * HDIM, b2v + l * 256, degf,
                nullptr, uHi, uLo, NN, HDIM, HDIM, HDIM, 0);

            // h = h + U@V2 + c2  -> split planes
            mgemm_k<3, 1, 1><<<gRes, blk, 0, stream>>>(
                nullptr, uHi, uLo, u2t, HDIM,
                nullptr, nullptr, nullptr, 0,
                ub2 + l * HDIM, nullptr, nullptr,
                nullptr, hHi, hLo, NN, HDIM, HDIM, 0, 0);
        }

        // out = h @ out_W + out_b (f32)
        mgemm_k<0, 1, 0><<<gOut, blk, 0, stream>>>(
            nullptr, hHi, hLo, wtOut, HDIM,
            nullptr, nullptr, nullptr, 0,
            outb, nullptr, nullptr,
            out_g, nullptr, nullptr, NN, NDIM, HDIM, 0, 0);
    }
}

// Round 6
// 1827.818 us; speedup vs baseline: 2.2607x; 1.1803x over previous
//
#include <hip/hip_runtime.h>

#define NN 20000     // nodes per graph
#define NE 320000    // edges per graph
#define NB 2         // graphs
#define HDIM 256     // hidden
#define NDIM 64      // node feature dim
#define EDIM 32      // edge feature dim
#define NL 4         // layers

typedef short short8 __attribute__((ext_vector_type(8)));
typedef float f32x4 __attribute__((ext_vector_type(4)));

__device__ __forceinline__ float gelu_af(float x) {
    float u = 0.7978845608028654f * (x + 0.044715f * x * x * x);
    float e = __expf(2.0f * u);
    float t = 1.0f - 2.0f / (e + 1.0f);
    return 0.5f * x * (1.0f + t);
}

__device__ __forceinline__ unsigned short f2bf(float f) {
    unsigned int x = __float_as_uint(f);
    unsigned int r = (x + 0x7fffu + ((x >> 16) & 1u)) >> 16;
    return (unsigned short)r;
}
__device__ __forceinline__ float bf2f(unsigned short h) {
    return __uint_as_float(((unsigned int)h) << 16);
}

// ---------------- weight transpose + bf16 convert (once per launch) ---------
__global__ __launch_bounds__(256) void tr_k(
    const float* __restrict__ inW, const float* __restrict__ mW1,
    const float* __restrict__ mW2, const float* __restrict__ uW1,
    const float* __restrict__ uW2, const float* __restrict__ outW,
    unsigned short* __restrict__ dst)
{
    const int id = blockIdx.z;
    const float* src; int K, N; size_t doff;
    if (id == 0)       { src = inW;  K = 64;  N = 256; doff = 0; }
    else if (id <= 4)  { int l = id - 1;  src = mW1 + (size_t)l * 544 * 256; K = 544; N = 256; doff = 16384   + (size_t)l * 139264; }
    else if (id <= 8)  { int l = id - 5;  src = mW2 + (size_t)l * 256 * 256; K = 256; N = 256; doff = 573440  + (size_t)l * 65536;  }
    else if (id <= 12) { int l = id - 9;  src = uW1 + (size_t)l * 512 * 256; K = 512; N = 256; doff = 835584  + (size_t)l * 131072; }
    else if (id <= 16) { int l = id - 13; src = uW2 + (size_t)l * 256 * 256; K = 256; N = 256; doff = 1359872 + (size_t)l * 65536;  }
    else               { src = outW; K = 256; N = 64;  doff = 1622016; }

    const int k0 = blockIdx.x * 32, n0 = blockIdx.y * 32;
    if (k0 >= K || n0 >= N) return;   // block-uniform

    __shared__ float tile[32][33];
    const int tx = threadIdx.x & 31, ty = threadIdx.x >> 5;
    #pragma unroll
    for (int i = 0; i < 4; ++i) {
        int k = k0 + ty + i * 8, n = n0 + tx;
        tile[ty + i * 8][tx] = (k < K && n < N) ? src[(size_t)k * N + n] : 0.f;
    }
    __syncthreads();
    #pragma unroll
    for (int i = 0; i < 4; ++i) {
        int n = n0 + ty + i * 8, k = k0 + tx;
        if (n < N && k < K) dst[doff + (size_t)n * K + k] = f2bf(tile[tx][ty + i * 8]);
    }
}

// ---------------- W2@V1b precompute: WT[n][k] = sum_j W2[k][j] V1b[j][n] ----
__global__ __launch_bounds__(256) void wv_k(
    const float* __restrict__ mW2, const float* __restrict__ uW1,
    unsigned short* __restrict__ w2v1bT)
{
    const int l = blockIdx.z;
    const float* W2  = mW2 + (size_t)l * 65536;
    const float* V1b = uW1 + (size_t)l * 131072 + 65536;   // rows 256.. of [512][256]
    const int n0 = blockIdx.x * 16, k0 = blockIdx.y * 16;
    const int tx = threadIdx.x & 15, ty = threadIdx.x >> 4;
    __shared__ float sW[16][17], sV[16][17];
    float acc = 0.f;
    for (int j0 = 0; j0 < 256; j0 += 16) {
        sW[ty][tx] = W2[(size_t)(k0 + ty) * 256 + j0 + tx];
        sV[ty][tx] = V1b[(size_t)(j0 + ty) * 256 + n0 + tx];
        __syncthreads();
        #pragma unroll
        for (int jj = 0; jj < 16; ++jj)
            acc = fmaf(sW[ty][jj], sV[jj][tx], acc);
        __syncthreads();
    }
    w2v1bT[(size_t)l * 65536 + (size_t)(n0 + tx) * 256 + (k0 + ty)] = f2bf(acc);
}

// ---------------- b2@V1b + fused bias512 build ------------------------------
__global__ void bv_k(const float* __restrict__ mb1, const float* __restrict__ mb2,
                     const float* __restrict__ uW1,
                     float* __restrict__ b2v, float* __restrict__ bias512)
{
    const int l = blockIdx.x, t = threadIdx.x;   // 512 threads
    if (t < 256) {
        const float* V1b = uW1 + (size_t)l * 131072 + 65536;
        const float* b2  = mb2 + l * 256;
        float s = 0.f;
        for (int j = 0; j < 256; ++j) s = fmaf(b2[j], V1b[(size_t)j * 256 + t], s);
        b2v[l * 256 + t] = s;
    }
    bias512[l * 512 + t] = (t < 256) ? 0.f : mb1[l * 256 + (t - 256)];
}

// ---------------- MFMA GEMM ------------------------------------------------
// ASPLIT=0: A is f32, runtime hi/lo split.  ASPLIT=1: A (and A2) pre-split planes.
// CSPLIT=0: C f32.  CSPLIT=1: C hi/lo bf16 planes (Ch/Cl).
// MODE 0: C = A@W + bias(optional)
// MODE 3: C = (Chi+Clo) + A@W + bias      (residual; A != C buffers)
// MODE 4: C = gelu(A@W + A2@W2 + degf[m]*bias2 + bias)
template <int MODE, int ASPLIT, int CSPLIT>
__global__ __launch_bounds__(256) void mgemm_k(
    const float* __restrict__ A,
    const unsigned short* __restrict__ Ah, const unsigned short* __restrict__ Al,
    const unsigned short* __restrict__ BT, int ldb,
    const unsigned short* __restrict__ A2h, const unsigned short* __restrict__ A2l,
    const unsigned short* __restrict__ BT2, int ldb2,
    const float* __restrict__ bias, const float* __restrict__ bias2,
    const float* __restrict__ degf,
    float* __restrict__ C, unsigned short* __restrict__ Ch, unsigned short* __restrict__ Cl,
    int M, int N, int K, int K2, int bkoff)
{
    __shared__ unsigned char smem[64 * 80 * 2 + 128 * 80];  // ahi, alo, bt (80B rows)
    unsigned char* ahi = smem;
    unsigned char* alo = smem + 64 * 80;
    unsigned char* btl = smem + 64 * 80 * 2;

    const int tid = threadIdx.x;
    const int bm = blockIdx.x * 64;
    const int bn = blockIdx.y * 128;
    const int w = tid >> 6, lane = tid & 63;
    const int wr = w >> 1, wc = w & 1;
    const int lrow = lane & 15, lg = lane >> 4;

    f32x4 acc[2][4];
    #pragma unroll
    for (int i = 0; i < 2; ++i)
        #pragma unroll
        for (int j = 0; j < 4; ++j) acc[i][j] = (f32x4){0.f, 0.f, 0.f, 0.f};

    const int t1 = K >> 5, t2 = K2 >> 5;
    for (int t = 0; t < t1 + t2; ++t) {
        int k0, lda, ldbv;
        const float* Ap; const unsigned short* Ahp; const unsigned short* Alp;
        const unsigned short* Bp;
        if (t < t1) { Ap = A;  Ahp = Ah;  Alp = Al;  Bp = BT;  k0 = t * 32;        lda = K;  ldbv = ldb;  }
        else        { Ap = nullptr; Ahp = A2h; Alp = A2l; Bp = BT2; k0 = (t - t1) * 32; lda = K2; ldbv = ldb2; }

        {   // stage A
            const int row = tid >> 2, kq = (tid & 3) * 8;
            const int m = bm + row;
            if (ASPLIT) {
                uint4 hv = make_uint4(0u, 0u, 0u, 0u), lv = hv;
                if (m < M) {
                    hv = *(const uint4*)&Ahp[(size_t)m * lda + k0 + kq];
                    lv = *(const uint4*)&Alp[(size_t)m * lda + k0 + kq];
                }
                *(uint4*)(ahi + row * 80 + kq * 2) = hv;
                *(uint4*)(alo + row * 80 + kq * 2) = lv;
            } else {
                float4 v0 = make_float4(0.f, 0.f, 0.f, 0.f), v1 = v0;
                if (m < M) {
                    v0 = *(const float4*)&Ap[(size_t)m * lda + k0 + kq];
                    v1 = *(const float4*)&Ap[(size_t)m * lda + k0 + kq + 4];
                }
                float vv[8] = {v0.x, v0.y, v0.z, v0.w, v1.x, v1.y, v1.z, v1.w};
                unsigned short hh[8], ll[8];
                #pragma unroll
                for (int j = 0; j < 8; ++j) {
                    hh[j] = f2bf(vv[j]);
                    ll[j] = f2bf(vv[j] - bf2f(hh[j]));
                }
                ushort4 ph0 = {hh[0], hh[1], hh[2], hh[3]}, ph1 = {hh[4], hh[5], hh[6], hh[7]};
                ushort4 pl0 = {ll[0], ll[1], ll[2], ll[3]}, pl1 = {ll[4], ll[5], ll[6], ll[7]};
                *(ushort4*)(ahi + row * 80 + kq * 2)     = ph0;
                *(ushort4*)(ahi + row * 80 + kq * 2 + 8) = ph1;
                *(ushort4*)(alo + row * 80 + kq * 2)     = pl0;
                *(ushort4*)(alo + row * 80 + kq * 2 + 8) = pl1;
            }
        }
        {   // stage B: 128 n-rows x 32 k bf16; fused-B via (n>>8)*bkoff column shift
            const int row = tid >> 1, half = tid & 1;
            const int n = bn + row;
            const unsigned short* brow = Bp + (size_t)(n & 255) * ldbv + (n >> 8) * bkoff;
            #pragma unroll
            for (int c = 0; c < 2; ++c) {
                const int q = half * 2 + c;
                uint4 d = make_uint4(0u, 0u, 0u, 0u);
                if (n < N) d = *(const uint4*)&brow[k0 + q * 8];
                *(uint4*)(btl + row * 80 + q * 16) = d;
            }
        }
        __syncthreads();

        short8 ah[2], al[2], bfr[4];
        #pragma unroll
        for (int mi = 0; mi < 2; ++mi) {
            const int r = wr * 32 + mi * 16 + lrow;
            ah[mi] = *(const short8*)(ahi + r * 80 + lg * 16);
            al[mi] = *(const short8*)(alo + r * 80 + lg * 16);
        }
        #pragma unroll
        for (int ni = 0; ni < 4; ++ni) {
            const int r = wc * 64 + ni * 16 + lrow;
            bfr[ni] = *(const short8*)(btl + r * 80 + lg * 16);
        }
        #pragma unroll
        for (int mi = 0; mi < 2; ++mi)
            #pragma unroll
            for (int ni = 0; ni < 4; ++ni) {
                acc[mi][ni] = __builtin_amdgcn_mfma_f32_16x16x32_bf16(ah[mi], bfr[ni], acc[mi][ni], 0, 0, 0);
                acc[mi][ni] = __builtin_amdgcn_mfma_f32_16x16x32_bf16(al[mi], bfr[ni], acc[mi][ni], 0, 0, 0);
            }
        __syncthreads();
    }

    // epilogue: D row = 4*lg + reg, col = lrow
    #pragma unroll
    for (int mi = 0; mi < 2; ++mi) {
        #pragma unroll
        for (int ni = 0; ni < 4; ++ni) {
            const int ncol = bn + wc * 64 + ni * 16 + lrow;
            if (ncol >= N) continue;
            const float bv = bias ? bias[ncol] : 0.f;
            const float b2vv = (MODE == 4) ? bias2[ncol] : 0.f;
            const int mbase = bm + wr * 32 + mi * 16 + lg * 4;
            #pragma unroll
            for (int r = 0; r < 4; ++r) {
                const int m = mbase + r;
                if (m >= M) continue;
                const size_t cb = (size_t)m * N + ncol;
                float v = acc[mi][ni][r];
                if (MODE == 0)      v += bv;
                else if (MODE == 3) v += bf2f(Ch[cb]) + bf2f(Cl[cb]) + bv;
                else                v = gelu_af(v + degf[m] * b2vv + bv);
                if (CSPLIT) {
                    unsigned short hi = f2bf(v);
                    unsigned short lo = f2bf(v - bf2f(hi));
                    Ch[cb] = hi; Cl[cb] = lo;
                } else {
                    C[cb] = v;
                }
            }
        }
    }
}

// ---------------- CSR build (counting sort by destination) -----------------
__global__ void hist_k(const int* __restrict__ ei, int* __restrict__ cnt) {
    int i = blockIdx.x * blockDim.x + threadIdx.x;
    if (i < NE) atomicAdd(&cnt[ei[2 * i + 1]], 1);
}

__global__ void scan_k(const int* __restrict__ cnt, int* __restrict__ row_ptr,
                       int* __restrict__ cursor, float* __restrict__ degf) {
    __shared__ int part[256];
    int tid = threadIdx.x;
    const int per = (NN + 255) >> 8;
    int s0 = tid * per;
    int s1 = s0 + per; if (s1 > NN) s1 = NN; if (s0 > NN) s0 = NN;
    int sum = 0;
    for (int i = s0; i < s1; ++i) sum += cnt[i];
    part[tid] = sum;
    __syncthreads();
    if (tid == 0) {
        int r = 0;
        for (int i = 0; i < 256; ++i) { int v = part[i]; part[i] = r; r += v; }
    }
    __syncthreads();
    int off = part[tid];
    for (int i = s0; i < s1; ++i) {
        int c = cnt[i];
        row_ptr[i] = off; cursor[i] = off; degf[i] = (float)c;
        off += c;
    }
    if (tid == 255) row_ptr[NN] = off;
}

__global__ void fill_k(const int* __restrict__ ei, int* __restrict__ cursor,
                       int* __restrict__ csr_src, int* __restrict__ csr_eid) {
    int i = blockIdx.x * blockDim.x + threadIdx.x;
    if (i < NE) {
        int s = ei[2 * i + 0];
        int d = ei[2 * i + 1];
        int pos = atomicAdd(&cursor[d], 1);
        csr_src[pos] = s;
        csr_eid[pos] = i;
    }
}

// ---------------- Edge aggregation v3: fused Ef-MFMA + aggregate ------------
// Per 32-position CSR chunk: stage gathered efeat rows (bf16) in LDS, MFMA
// against LDS-resident W1c -> Ef chunk in LDS, then waves consume:
// Sagg[d] = sum_p gelu(T12[src_p][0:256] + T12[d][256:512] + Ef[p]) -> split bf16
// Batched over graphs: g = blockIdx.x / (NN/4).
__global__ __launch_bounds__(256) void edge_agg3_k(
    const float* __restrict__ T12, const float* __restrict__ efeat,
    const unsigned short* __restrict__ w1t,   // [256][544] bf16, W1c at col 512
    const int* __restrict__ csr_src, const int* __restrict__ csr_eid,
    const int* __restrict__ row_ptr,
    unsigned short* __restrict__ Shi, unsigned short* __restrict__ Slo)
{
    __shared__ unsigned char w1c[256 * 80];     // 20480 B
    __shared__ unsigned char efa[32 * 80];      //  2560 B
    __shared__ unsigned short efo[32 * 264];    // 16896 B (264-stride: bank-spread)

    const int tid = threadIdx.x;
    const int g   = blockIdx.x / (NN / 4);
    const int blk = blockIdx.x % (NN / 4);

    const float* T12g = T12 + (size_t)g * NN * 512;
    const float* efg  = efeat + (size_t)g * NE * EDIM;
    const int* csG    = csr_src + (size_t)g * NE;
    const int* ceG    = csr_eid + (size_t)g * NE;
    const int* rpG    = row_ptr + (size_t)g * (NN + 1);

    {   // stage W1c: thread t copies row t (32 k = 64B)
        const unsigned short* srcw = w1t + (size_t)tid * 544 + 512;
        uint4 a = *(const uint4*)(srcw);
        uint4 b = *(const uint4*)(srcw + 8);
        uint4 c = *(const uint4*)(srcw + 16);
        uint4 d = *(const uint4*)(srcw + 24);
        *(uint4*)(w1c + tid * 80 +  0) = a;
        *(uint4*)(w1c + tid * 80 + 16) = b;
        *(uint4*)(w1c + tid * 80 + 32) = c;
        *(uint4*)(w1c + tid * 80 + 48) = d;
    }

    const int wave = tid >> 6, lane = tid & 63;
    const int lrow = lane & 15, lg = lane >> 4;
    const int d = blk * 4 + wave;
    const int dstart = rpG[d], dend = rpG[d + 1];
    const int P0 = rpG[blk * 4], P1 = rpG[blk * 4 + 4];   // block-uniform
    const int c0 = lane * 4;

    const float4 hd = *(const float4*)&T12g[(size_t)d * 512 + 256 + c0];
    float4 acc = make_float4(0.f, 0.f, 0.f, 0.f);

    const int mf = wave >> 1, ch = wave & 1;

    for (int P = P0; P < P1; P += 32) {
        // ---- stage efa: 32 gathered efeat rows -> bf16 (threads 0-127) ----
        if (tid < 128) {
            const int r = tid >> 2, kq = (tid & 3) * 8;
            int pos = P + r; if (pos >= P1) pos = P1 - 1;
            const int eid = ceG[pos];
            float4 v0 = *(const float4*)&efg[(size_t)eid * EDIM + kq];
            float4 v1 = *(const float4*)&efg[(size_t)eid * EDIM + kq + 4];
            ushort4 p0 = {f2bf(v0.x), f2bf(v0.y), f2bf(v0.z), f2bf(v0.w)};
            ushort4 p1 = {f2bf(v1.x), f2bf(v1.y), f2bf(v1.z), f2bf(v1.w)};
            *(ushort4*)(efa + r * 80 + kq * 2)     = p0;
            *(ushort4*)(efa + r * 80 + kq * 2 + 8) = p1;
        }
        __syncthreads();

        // ---- MFMA: wave (mf,ch) computes rows [mf*16,+16) x cols [ch*128,+128)
        {
            short8 af = *(const short8*)(efa + (mf * 16 + lrow) * 80 + lg * 16);
            f32x4 a8[8];
            #pragma unroll
            for (int ni = 0; ni < 8; ++ni) {
                short8 bfrag = *(const short8*)(w1c + (ch * 128 + ni * 16 + lrow) * 80 + lg * 16);
                a8[ni] = (f32x4){0.f, 0.f, 0.f, 0.f};
                a8[ni] = __builtin_amdgcn_mfma_f32_16x16x32_bf16(af, bfrag, a8[ni], 0, 0, 0);
            }
            #pragma unroll
            for (int ni = 0; ni < 8; ++ni)
                #pragma unroll
                for (int r = 0; r < 4; ++r)
                    efo[(mf * 16 + 4 * lg + r) * 264 + ch * 128 + ni * 16 + lrow] = f2bf(a8[ni][r]);
        }
        __syncthreads();

        // ---- consume: this wave's node's positions within [P, P+32) ----
        {
            int p = dstart > P ? dstart : P;
            const int e = (dend < P + 32) ? dend : (P + 32);
            for (; p + 2 <= e; p += 2) {
                const int s0 = __builtin_amdgcn_readfirstlane(csG[p]);
                const int s1 = __builtin_amdgcn_readfirstlane(csG[p + 1]);
                float4 h0 = *(const float4*)&T12g[(size_t)s0 * 512 + c0];
                float4 h1 = *(const float4*)&T12g[(size_t)s1 * 512 + c0];
                ushort4 e0 = *(const ushort4*)&efo[(p - P) * 264 + c0];
                ushort4 e1 = *(const ushort4*)&efo[(p + 1 - P) * 264 + c0];
                acc.x += gelu_af(h0.x + hd.x + bf2f(e0.x));
                acc.y += gelu_af(h0.y + hd.y + bf2f(e0.y));
                acc.z += gelu_af(h0.z + hd.z + bf2f(e0.z));
                acc.w += gelu_af(h0.w + hd.w + bf2f(e0.w));
                acc.x += gelu_af(h1.x + hd.x + bf2f(e1.x));
                acc.y += gelu_af(h1.y + hd.y + bf2f(e1.y));
                acc.z += gelu_af(h1.z + hd.z + bf2f(e1.z));
                acc.w += gelu_af(h1.w + hd.w + bf2f(e1.w));
            }
            if (p < e) {
                const int s0 = __builtin_amdgcn_readfirstlane(csG[p]);
                float4 h0 = *(const float4*)&T12g[(size_t)s0 * 512 + c0];
                ushort4 e0 = *(const ushort4*)&efo[(p - P) * 264 + c0];
                acc.x += gelu_af(h0.x + hd.x + bf2f(e0.x));
                acc.y += gelu_af(h0.y + hd.y + bf2f(e0.y));
                acc.z += gelu_af(h0.z + hd.z + bf2f(e0.z));
                acc.w += gelu_af(h0.w + hd.w + bf2f(e0.w));
            }
        }
        __syncthreads();
    }

    ushort4 ho, lo;
    ho.x = f2bf(acc.x); lo.x = f2bf(acc.x - bf2f(ho.x));
    ho.y = f2bf(acc.y); lo.y = f2bf(acc.y - bf2f(ho.y));
    ho.z = f2bf(acc.z); lo.z = f2bf(acc.z - bf2f(ho.z));
    ho.w = f2bf(acc.w); lo.w = f2bf(acc.w - bf2f(ho.w));
    *(ushort4*)&Shi[((size_t)g * NN + d) * HDIM + c0] = ho;
    *(ushort4*)&Slo[((size_t)g * NN + d) * HDIM + c0] = lo;
}

// ---------------- launcher ---------------------------------------------------
extern "C" void kernel_launch(void* const* d_in, const int* in_sizes, int n_in,
                              void* d_out, int out_size, void* d_ws, size_t ws_size,
                              hipStream_t stream)
{
    const float* nf    = (const float*)d_in[0];
    const int*   ei    = (const int*)  d_in[1];
    const float* efeat = (const float*)d_in[2];
    const float* inW   = (const float*)d_in[3];
    const float* inb   = (const float*)d_in[4];
    const float* mW1   = (const float*)d_in[5];
    const float* mb1   = (const float*)d_in[6];
    const float* mW2   = (const float*)d_in[7];
    const float* mb2   = (const float*)d_in[8];
    const float* uW1   = (const float*)d_in[9];
    const float* ub1   = (const float*)d_in[10];
    const float* uW2   = (const float*)d_in[11];
    const float* ub2   = (const float*)d_in[12];
    const float* outW  = (const float*)d_in[13];
    const float* outb  = (const float*)d_in[14];
    float* outp = (float*)d_out;

    const int MT = NB * NN;   // 40000 batched rows

    char* p = (char*)d_ws;
    auto carve = [&](size_t bytes) -> void* {
        void* r = (void*)p;
        p += (bytes + 255) & ~(size_t)255;
        return r;
    };
    unsigned short* hS  = (unsigned short*)carve((size_t)2 * MT * HDIM * 2);  // hi|lo planes
    unsigned short* T3S = (unsigned short*)carve((size_t)2 * MT * HDIM * 2);
    float* T12 = (float*)carve((size_t)MT * 512 * 4);     // Hs|Hd fused, f32 (82 MB)
    unsigned short* US = (unsigned short*)T12;            // alias: U planes reuse dead T12
    int* csr_src = (int*)carve((size_t)NB * NE * 4);
    int* csr_eid = (int*)carve((size_t)NB * NE * 4);
    int* row_ptr = (int*)carve((size_t)NB * (NN + 1) * 4);
    int* cursor  = (int*)carve((size_t)NB * NN * 4);
    int* cnt     = (int*)carve((size_t)NB * NN * 4);
    float* degf  = (float*)carve((size_t)MT * 4);
    unsigned short* wtbuf  = (unsigned short*)carve((size_t)1638400 * 2);
    unsigned short* w2v1bT = (unsigned short*)carve((size_t)4 * 65536 * 2);
    float* b2v     = (float*)carve((size_t)4 * 256 * 4);
    float* bias512 = (float*)carve((size_t)4 * 512 * 4);
    (void)ws_size; (void)in_sizes; (void)n_in; (void)out_size;

    unsigned short* hHi  = hS;   unsigned short* hLo  = hS  + (size_t)MT * HDIM;
    unsigned short* t3Hi = T3S;  unsigned short* t3Lo = T3S + (size_t)MT * HDIM;
    unsigned short* uHi  = US;   unsigned short* uLo  = US  + (size_t)MT * HDIM;

    const dim3 blk(256);
    const dim3 gIn(625, 2), gHsHd(625, 4), gU(625, 2), gRes(625, 2), gOut(625, 1);
    const dim3 gE(NB * NN / 4);   // 10000, both graphs

    // once: weight transforms
    tr_k<<<dim3(17, 8, 18), blk, 0, stream>>>(inW, mW1, mW2, uW1, uW2, outW, wtbuf);
    wv_k<<<dim3(16, 16, 4), blk, 0, stream>>>(mW2, uW1, w2v1bT);
    bv_k<<<dim3(4), dim3(512), 0, stream>>>(mb1, mb2, uW1, b2v, bias512);

    const unsigned short* wtIn  = wtbuf;
    const unsigned short* wtW1  = wtbuf + 16384;
    const unsigned short* wtU1  = wtbuf + 835584;
    const unsigned short* wtU2  = wtbuf + 1359872;
    const unsigned short* wtOut = wtbuf + 1622016;

    // CSR for both graphs
    hipMemsetAsync(cnt, 0, (size_t)NB * NN * sizeof(int), stream);
    for (int g = 0; g < NB; ++g) {
        const int* ei_g = ei + (size_t)g * NE * 2;
        hist_k<<<(NE + 255) / 256, blk, 0, stream>>>(ei_g, cnt + g * NN);
        scan_k<<<1, blk, 0, stream>>>(cnt + g * NN, row_ptr + g * (NN + 1),
                                      cursor + g * NN, degf + g * NN);
        fill_k<<<(NE + 255) / 256, blk, 0, stream>>>(ei_g, cursor + g * NN,
                                                     csr_src + (size_t)g * NE,
                                                     csr_eid + (size_t)g * NE);
    }

    // h = nf @ in_W + in_b  (batched M=40000) -> split planes
    mgemm_k<0, 0, 1><<<gIn, blk, 0, stream>>>(
        nf, nullptr, nullptr, wtIn, NDIM,
        nullptr, nullptr, nullptr, 0,
        inb, nullptr, nullptr,
        nullptr, hHi, hLo, MT, HDIM, NDIM, 0, 0);

    for (int l = 0; l < NL; ++l) {
        const unsigned short* w1t = wtW1 + (size_t)l * 139264;
        const unsigned short* u1t = wtU1 + (size_t)l * 131072;
        const unsigned short* u2t = wtU2 + (size_t)l * 65536;

        // T12 = h @ [W1a|W1b] + [0,b1]   (batched, fused N=512)
        mgemm_k<0, 1, 0><<<gHsHd, blk, 0, stream>>>(
            nullptr, hHi, hLo, w1t, 544,
            nullptr, nullptr, nullptr, 0,
            bias512 + l * 512, nullptr, nullptr,
            T12, nullptr, nullptr, MT, 512, HDIM, 0, 256);

        // Sagg (fused Ef MFMA + aggregate, both graphs) -> T3 split planes
        edge_agg3_k<<<gE, blk, 0, stream>>>(T12, efeat, w1t,
                                            csr_src, csr_eid, row_ptr,
                                            t3Hi, t3Lo);

        // U = gelu(h@V1a + Sagg@(W2@V1b) + deg*(b2@V1b) + c1) -> US (aliases T12)
        mgemm_k<4, 1, 1><<<gU, blk, 0, stream>>>(
            nullptr, hHi, hLo, u1t, 512,
            t3Hi, t3Lo, w2v1bT + (size_t)l * 65536, 256,
            ub1 + l * HDIM, b2v + l * 256, degf,
            nullptr, uHi, uLo, MT, HDIM, HDIM, HDIM, 0);

        // h = h + U@V2 + c2  -> split planes
        mgemm_k<3, 1, 1><<<gRes, blk, 0, stream>>>(
            nullptr, uHi, uLo, u2t, HDIM,
            nullptr, nullptr, nullptr, 0,
            ub2 + l * HDIM, nullptr, nullptr,
            nullptr, hHi, hLo, MT, HDIM, HDIM, 0, 0);
    }

    // out = h @ out_W + out_b (f32, batched)
    mgemm_k<0, 1, 0><<<gOut, blk, 0, stream>>>(
        nullptr, hHi, hLo, wtOut, HDIM,
        nullptr, nullptr, nullptr, 0,
        outb, nullptr, nullptr,
        outp, nullptr, nullptr, MT, NDIM, HDIM, 0, 0);
}

// Round 7
// 1571.480 us; speedup vs baseline: 2.6294x; 1.1631x over previous
//
#include <hip/hip_runtime.h>

#define NN 20000     // nodes per graph
#define NE 320000    // edges per graph
#define NB 2         // graphs
#define HDIM 256     // hidden
#define NDIM 64      // node feature dim
#define EDIM 32      // edge feature dim
#define NL 4         // layers

typedef short short8 __attribute__((ext_vector_type(8)));
typedef float f32x4 __attribute__((ext_vector_type(4)));

// gelu(x) = x * sigmoid(2*0.7978...*(x+0.044715x^3)) = x - x/(e+1),
// e = exp2(2.3022082*(x+0.044715x^3)).  8 VALU incl 2 trans.
__device__ __forceinline__ float gelu_af(float x) {
    float x3 = x * x * x;
    float e = exp2f(2.3022082f * fmaf(0.044715f, x3, x));
    return fmaf(-x, __builtin_amdgcn_rcpf(e + 1.0f), x);
}

__device__ __forceinline__ unsigned short f2bf(float f) {
    unsigned int x = __float_as_uint(f);
    unsigned int r = (x + 0x7fffu + ((x >> 16) & 1u)) >> 16;
    return (unsigned short)r;
}
__device__ __forceinline__ float bf2f(unsigned short h) {
    return __uint_as_float(((unsigned int)h) << 16);
}

// ---------------- weight transpose + bf16 convert (once per launch) ---------
__global__ __launch_bounds__(256) void tr_k(
    const float* __restrict__ inW, const float* __restrict__ mW1,
    const float* __restrict__ mW2, const float* __restrict__ uW1,
    const float* __restrict__ uW2, const float* __restrict__ outW,
    unsigned short* __restrict__ dst)
{
    const int id = blockIdx.z;
    const float* src; int K, N; size_t doff;
    if (id == 0)       { src = inW;  K = 64;  N = 256; doff = 0; }
    else if (id <= 4)  { int l = id - 1;  src = mW1 + (size_t)l * 544 * 256; K = 544; N = 256; doff = 16384   + (size_t)l * 139264; }
    else if (id <= 8)  { int l = id - 5;  src = mW2 + (size_t)l * 256 * 256; K = 256; N = 256; doff = 573440  + (size_t)l * 65536;  }
    else if (id <= 12) { int l = id - 9;  src = uW1 + (size_t)l * 512 * 256; K = 512; N = 256; doff = 835584  + (size_t)l * 131072; }
    else if (id <= 16) { int l = id - 13; src = uW2 + (size_t)l * 256 * 256; K = 256; N = 256; doff = 1359872 + (size_t)l * 65536;  }
    else               { src = outW; K = 256; N = 64;  doff = 1622016; }

    const int k0 = blockIdx.x * 32, n0 = blockIdx.y * 32;
    if (k0 >= K || n0 >= N) return;   // block-uniform

    __shared__ float tile[32][33];
    const int tx = threadIdx.x & 31, ty = threadIdx.x >> 5;
    #pragma unroll
    for (int i = 0; i < 4; ++i) {
        int k = k0 + ty + i * 8, n = n0 + tx;
        tile[ty + i * 8][tx] = (k < K && n < N) ? src[(size_t)k * N + n] : 0.f;
    }
    __syncthreads();
    #pragma unroll
    for (int i = 0; i < 4; ++i) {
        int n = n0 + ty + i * 8, k = k0 + tx;
        if (n < N && k < K) dst[doff + (size_t)n * K + k] = f2bf(tile[tx][ty + i * 8]);
    }
}

// ---------------- W2@V1b precompute: WT[n][k] = sum_j W2[k][j] V1b[j][n] ----
__global__ __launch_bounds__(256) void wv_k(
    const float* __restrict__ mW2, const float* __restrict__ uW1,
    unsigned short* __restrict__ w2v1bT)
{
    const int l = blockIdx.z;
    const float* W2  = mW2 + (size_t)l * 65536;
    const float* V1b = uW1 + (size_t)l * 131072 + 65536;   // rows 256.. of [512][256]
    const int n0 = blockIdx.x * 16, k0 = blockIdx.y * 16;
    const int tx = threadIdx.x & 15, ty = threadIdx.x >> 4;
    __shared__ float sW[16][17], sV[16][17];
    float acc = 0.f;
    for (int j0 = 0; j0 < 256; j0 += 16) {
        sW[ty][tx] = W2[(size_t)(k0 + ty) * 256 + j0 + tx];
        sV[ty][tx] = V1b[(size_t)(j0 + ty) * 256 + n0 + tx];
        __syncthreads();
        #pragma unroll
        for (int jj = 0; jj < 16; ++jj)
            acc = fmaf(sW[ty][jj], sV[jj][tx], acc);
        __syncthreads();
    }
    w2v1bT[(size_t)l * 65536 + (size_t)(n0 + tx) * 256 + (k0 + ty)] = f2bf(acc);
}

// ---------------- b2@V1b + fused bias512 build ------------------------------
__global__ void bv_k(const float* __restrict__ mb1, const float* __restrict__ mb2,
                     const float* __restrict__ uW1,
                     float* __restrict__ b2v, float* __restrict__ bias512)
{
    const int l = blockIdx.x, t = threadIdx.x;   // 512 threads
    if (t < 256) {
        const float* V1b = uW1 + (size_t)l * 131072 + 65536;
        const float* b2  = mb2 + l * 256;
        float s = 0.f;
        for (int j = 0; j < 256; ++j) s = fmaf(b2[j], V1b[(size_t)j * 256 + t], s);
        b2v[l * 256 + t] = s;
    }
    bias512[l * 512 + t] = (t < 256) ? 0.f : mb1[l * 256 + (t - 256)];
}

// ---------------- MFMA GEMM ------------------------------------------------
// ASPLIT=0: A is f32, runtime hi/lo split.  ASPLIT=1: A (and A2) pre-split planes.
// CSPLIT=0: C f32.  CSPLIT=1: C hi/lo bf16 planes (Ch/Cl).
// MODE 0: C = A@W + bias(optional)
// MODE 3: C = (Chi+Clo) + A@W + bias      (residual; A != C buffers)
// MODE 4: C = gelu(A@W + A2@W2 + degf[m]*bias2 + bias)
template <int MODE, int ASPLIT, int CSPLIT>
__global__ __launch_bounds__(256) void mgemm_k(
    const float* __restrict__ A,
    const unsigned short* __restrict__ Ah, const unsigned short* __restrict__ Al,
    const unsigned short* __restrict__ BT, int ldb,
    const unsigned short* __restrict__ A2h, const unsigned short* __restrict__ A2l,
    const unsigned short* __restrict__ BT2, int ldb2,
    const float* __restrict__ bias, const float* __restrict__ bias2,
    const float* __restrict__ degf,
    float* __restrict__ C, unsigned short* __restrict__ Ch, unsigned short* __restrict__ Cl,
    int M, int N, int K, int K2, int bkoff)
{
    __shared__ unsigned char smem[64 * 80 * 2 + 128 * 80];  // ahi, alo, bt (80B rows)
    unsigned char* ahi = smem;
    unsigned char* alo = smem + 64 * 80;
    unsigned char* btl = smem + 64 * 80 * 2;

    const int tid = threadIdx.x;
    const int bm = blockIdx.x * 64;
    const int bn = blockIdx.y * 128;
    const int w = tid >> 6, lane = tid & 63;
    const int wr = w >> 1, wc = w & 1;
    const int lrow = lane & 15, lg = lane >> 4;

    f32x4 acc[2][4];
    #pragma unroll
    for (int i = 0; i < 2; ++i)
        #pragma unroll
        for (int j = 0; j < 4; ++j) acc[i][j] = (f32x4){0.f, 0.f, 0.f, 0.f};

    const int t1 = K >> 5, t2 = K2 >> 5;
    for (int t = 0; t < t1 + t2; ++t) {
        int k0, lda, ldbv;
        const float* Ap; const unsigned short* Ahp; const unsigned short* Alp;
        const unsigned short* Bp;
        if (t < t1) { Ap = A;  Ahp = Ah;  Alp = Al;  Bp = BT;  k0 = t * 32;        lda = K;  ldbv = ldb;  }
        else        { Ap = nullptr; Ahp = A2h; Alp = A2l; Bp = BT2; k0 = (t - t1) * 32; lda = K2; ldbv = ldb2; }

        {   // stage A
            const int row = tid >> 2, kq = (tid & 3) * 8;
            const int m = bm + row;
            if (ASPLIT) {
                uint4 hv = make_uint4(0u, 0u, 0u, 0u), lv = hv;
                if (m < M) {
                    hv = *(const uint4*)&Ahp[(size_t)m * lda + k0 + kq];
                    lv = *(const uint4*)&Alp[(size_t)m * lda + k0 + kq];
                }
                *(uint4*)(ahi + row * 80 + kq * 2) = hv;
                *(uint4*)(alo + row * 80 + kq * 2) = lv;
            } else {
                float4 v0 = make_float4(0.f, 0.f, 0.f, 0.f), v1 = v0;
                if (m < M) {
                    v0 = *(const float4*)&Ap[(size_t)m * lda + k0 + kq];
                    v1 = *(const float4*)&Ap[(size_t)m * lda + k0 + kq + 4];
                }
                float vv[8] = {v0.x, v0.y, v0.z, v0.w, v1.x, v1.y, v1.z, v1.w};
                unsigned short hh[8], ll[8];
                #pragma unroll
                for (int j = 0; j < 8; ++j) {
                    hh[j] = f2bf(vv[j]);
                    ll[j] = f2bf(vv[j] - bf2f(hh[j]));
                }
                ushort4 ph0 = {hh[0], hh[1], hh[2], hh[3]}, ph1 = {hh[4], hh[5], hh[6], hh[7]};
                ushort4 pl0 = {ll[0], ll[1], ll[2], ll[3]}, pl1 = {ll[4], ll[5], ll[6], ll[7]};
                *(ushort4*)(ahi + row * 80 + kq * 2)     = ph0;
                *(ushort4*)(ahi + row * 80 + kq * 2 + 8) = ph1;
                *(ushort4*)(alo + row * 80 + kq * 2)     = pl0;
                *(ushort4*)(alo + row * 80 + kq * 2 + 8) = pl1;
            }
        }
        {   // stage B: 128 n-rows x 32 k bf16; fused-B via (n>>8)*bkoff column shift
            const int row = tid >> 1, half = tid & 1;
            const int n = bn + row;
            const unsigned short* brow = Bp + (size_t)(n & 255) * ldbv + (n >> 8) * bkoff;
            #pragma unroll
            for (int c = 0; c < 2; ++c) {
                const int q = half * 2 + c;
                uint4 d = make_uint4(0u, 0u, 0u, 0u);
                if (n < N) d = *(const uint4*)&brow[k0 + q * 8];
                *(uint4*)(btl + row * 80 + q * 16) = d;
            }
        }
        __syncthreads();

        short8 ah[2], al[2], bfr[4];
        #pragma unroll
        for (int mi = 0; mi < 2; ++mi) {
            const int r = wr * 32 + mi * 16 + lrow;
            ah[mi] = *(const short8*)(ahi + r * 80 + lg * 16);
            al[mi] = *(const short8*)(alo + r * 80 + lg * 16);
        }
        #pragma unroll
        for (int ni = 0; ni < 4; ++ni) {
            const int r = wc * 64 + ni * 16 + lrow;
            bfr[ni] = *(const short8*)(btl + r * 80 + lg * 16);
        }
        #pragma unroll
        for (int mi = 0; mi < 2; ++mi)
            #pragma unroll
            for (int ni = 0; ni < 4; ++ni) {
                acc[mi][ni] = __builtin_amdgcn_mfma_f32_16x16x32_bf16(ah[mi], bfr[ni], acc[mi][ni], 0, 0, 0);
                acc[mi][ni] = __builtin_amdgcn_mfma_f32_16x16x32_bf16(al[mi], bfr[ni], acc[mi][ni], 0, 0, 0);
            }
        __syncthreads();
    }

    // epilogue: D row = 4*lg + reg, col = lrow
    #pragma unroll
    for (int mi = 0; mi < 2; ++mi) {
        #pragma unroll
        for (int ni = 0; ni < 4; ++ni) {
            const int ncol = bn + wc * 64 + ni * 16 + lrow;
            if (ncol >= N) continue;
            const float bv = bias ? bias[ncol] : 0.f;
            const float b2vv = (MODE == 4) ? bias2[ncol] : 0.f;
            const int mbase = bm + wr * 32 + mi * 16 + lg * 4;
            #pragma unroll
            for (int r = 0; r < 4; ++r) {
                const int m = mbase + r;
                if (m >= M) continue;
                const size_t cb = (size_t)m * N + ncol;
                float v = acc[mi][ni][r];
                if (MODE == 0)      v += bv;
                else if (MODE == 3) v += bf2f(Ch[cb]) + bf2f(Cl[cb]) + bv;
                else                v = gelu_af(v + degf[m] * b2vv + bv);
                if (CSPLIT) {
                    unsigned short hi = f2bf(v);
                    unsigned short lo = f2bf(v - bf2f(hi));
                    Ch[cb] = hi; Cl[cb] = lo;
                } else {
                    C[cb] = v;
                }
            }
        }
    }
}

// ---------------- CSR build (counting sort by destination) -----------------
__global__ void hist_k(const int* __restrict__ ei, int* __restrict__ cnt) {
    int i = blockIdx.x * blockDim.x + threadIdx.x;
    if (i < NE) atomicAdd(&cnt[ei[2 * i + 1]], 1);
}

__global__ void scan_k(const int* __restrict__ cnt, int* __restrict__ row_ptr,
                       int* __restrict__ cursor, float* __restrict__ degf) {
    __shared__ int part[256];
    int tid = threadIdx.x;
    const int per = (NN + 255) >> 8;
    int s0 = tid * per;
    int s1 = s0 + per; if (s1 > NN) s1 = NN; if (s0 > NN) s0 = NN;
    int sum = 0;
    for (int i = s0; i < s1; ++i) sum += cnt[i];
    part[tid] = sum;
    __syncthreads();
    if (tid == 0) {
        int r = 0;
        for (int i = 0; i < 256; ++i) { int v = part[i]; part[i] = r; r += v; }
    }
    __syncthreads();
    int off = part[tid];
    for (int i = s0; i < s1; ++i) {
        int c = cnt[i];
        row_ptr[i] = off; cursor[i] = off; degf[i] = (float)c;
        off += c;
    }
    if (tid == 255) row_ptr[NN] = off;
}

__global__ void fill_k(const int* __restrict__ ei, int* __restrict__ cursor,
                       int* __restrict__ csr_src, int* __restrict__ csr_eid) {
    int i = blockIdx.x * blockDim.x + threadIdx.x;
    if (i < NE) {
        int s = ei[2 * i + 0];
        int d = ei[2 * i + 1];
        int pos = atomicAdd(&cursor[d], 1);
        csr_src[pos] = s;
        csr_eid[pos] = i;
    }
}

// ---------------- Edge aggregation v4: fused Ef-MFMA + aggregate ------------
// Per 32-position CSR chunk: stage gathered efeat rows (bf16) + chunk src ids
// in LDS, MFMA against REGISTER-resident W1c fragments -> Ef chunk in LDS,
// then waves consume with 4-wide gather ILP:
// Sagg[d] = sum_p gelu(T12[src_p][0:256] + T12[d][256:512] + Ef[p]) -> split bf16
// Batched over graphs: g = blockIdx.x / (NN/4).  LDS 19.6KB -> 8 blocks/CU.
__global__ __launch_bounds__(256) void edge_agg4_k(
    const float* __restrict__ T12, const float* __restrict__ efeat,
    const unsigned short* __restrict__ w1t,   // [256][544] bf16, W1c at col 512
    const int* __restrict__ csr_src, const int* __restrict__ csr_eid,
    const int* __restrict__ row_ptr,
    unsigned short* __restrict__ Shi, unsigned short* __restrict__ Slo)
{
    __shared__ unsigned char efa[32 * 80];      //  2560 B staged efeat bf16
    __shared__ unsigned short efo[32 * 264];    // 16896 B Ef chunk bf16
    __shared__ int scs[32];                     //   128 B chunk src ids

    const int tid = threadIdx.x;
    const int g   = blockIdx.x / (NN / 4);
    const int blk = blockIdx.x % (NN / 4);

    const float* T12g = T12 + (size_t)g * NN * 512;
    const float* efg  = efeat + (size_t)g * NE * EDIM;
    const int* csG    = csr_src + (size_t)g * NE;
    const int* ceG    = csr_eid + (size_t)g * NE;
    const int* rpG    = row_ptr + (size_t)g * (NN + 1);

    const int wave = tid >> 6, lane = tid & 63;
    const int lrow = lane & 15, lg = lane >> 4;
    const int d = blk * 4 + wave;
    const int dstart = rpG[d], dend = rpG[d + 1];
    const int P0 = rpG[blk * 4], P1 = rpG[blk * 4 + 4];   // block-uniform
    const int c0 = lane * 4;
    const int mf = wave >> 1, ch = wave & 1;

    // W1c B-fragments in registers: tile ni covers cols ch*128+ni*16+lrow
    short8 bfrag[8];
    #pragma unroll
    for (int ni = 0; ni < 8; ++ni)
        bfrag[ni] = *(const short8*)&w1t[(size_t)(ch * 128 + ni * 16 + lrow) * 544 + 512 + lg * 8];

    const float4 hd = *(const float4*)&T12g[(size_t)d * 512 + 256 + c0];
    float4 acc = make_float4(0.f, 0.f, 0.f, 0.f);

    for (int P = P0; P < P1; P += 32) {
        // ---- stage efa (32 rows x 32 k bf16, all 256 threads) + scs --------
        {
            const int r = tid >> 3, kq = (tid & 7) * 4;
            int pos = P + r; if (pos >= P1) pos = P1 - 1;
            const int eid = ceG[pos];
            float4 v = *(const float4*)&efg[(size_t)eid * EDIM + kq];
            ushort4 pk = {f2bf(v.x), f2bf(v.y), f2bf(v.z), f2bf(v.w)};
            *(ushort4*)(efa + r * 80 + kq * 2) = pk;
            if (tid < 32) {
                int q = P + tid; if (q >= P1) q = P1 - 1;
                scs[tid] = csG[q];
            }
        }
        __syncthreads();

        // ---- MFMA: wave (mf,ch) -> rows [mf*16,+16) x cols [ch*128,+128) ---
        {
            short8 af = *(const short8*)(efa + (mf * 16 + lrow) * 80 + lg * 16);
            #pragma unroll
            for (int ni = 0; ni < 8; ++ni) {
                f32x4 a4 = (f32x4){0.f, 0.f, 0.f, 0.f};
                a4 = __builtin_amdgcn_mfma_f32_16x16x32_bf16(af, bfrag[ni], a4, 0, 0, 0);
                #pragma unroll
                for (int r = 0; r < 4; ++r)
                    efo[(mf * 16 + 4 * lg + r) * 264 + ch * 128 + ni * 16 + lrow] = f2bf(a4[r]);
            }
        }
        __syncthreads();

        // ---- consume: 4-wide gather ILP over this wave's positions ---------
        {
            int p = dstart > P ? dstart : P;
            const int e = (dend < P + 32) ? dend : (P + 32);
            for (; p < e; p += 4) {
                const int nc = e - p;
                int sj[4];
                #pragma unroll
                for (int j = 0; j < 4; ++j) {
                    const int q = p + ((j < nc) ? j : 0);
                    sj[j] = __builtin_amdgcn_readfirstlane(scs[q - P]);
                }
                float4 hs[4]; ushort4 ef[4];
                #pragma unroll
                for (int j = 0; j < 4; ++j) {
                    const int q = p + ((j < nc) ? j : 0);
                    hs[j] = *(const float4*)&T12g[(size_t)sj[j] * 512 + c0];
                    ef[j] = *(const ushort4*)&efo[(q - P) * 264 + c0];
                }
                #pragma unroll
                for (int j = 0; j < 4; ++j) {
                    if (j < nc) {   // wave-uniform predicate
                        acc.x += gelu_af(hs[j].x + hd.x + bf2f(ef[j].x));
                        acc.y += gelu_af(hs[j].y + hd.y + bf2f(ef[j].y));
                        acc.z += gelu_af(hs[j].z + hd.z + bf2f(ef[j].z));
                        acc.w += gelu_af(hs[j].w + hd.w + bf2f(ef[j].w));
                    }
                }
            }
        }
        __syncthreads();
    }

    ushort4 ho, lo;
    ho.x = f2bf(acc.x); lo.x = f2bf(acc.x - bf2f(ho.x));
    ho.y = f2bf(acc.y); lo.y = f2bf(acc.y - bf2f(ho.y));
    ho.z = f2bf(acc.z); lo.z = f2bf(acc.z - bf2f(ho.z));
    ho.w = f2bf(acc.w); lo.w = f2bf(acc.w - bf2f(ho.w));
    *(ushort4*)&Shi[((size_t)g * NN + d) * HDIM + c0] = ho;
    *(ushort4*)&Slo[((size_t)g * NN + d) * HDIM + c0] = lo;
}

// ---------------- launcher ---------------------------------------------------
extern "C" void kernel_launch(void* const* d_in, const int* in_sizes, int n_in,
                              void* d_out, int out_size, void* d_ws, size_t ws_size,
                              hipStream_t stream)
{
    const float* nf    = (const float*)d_in[0];
    const int*   ei    = (const int*)  d_in[1];
    const float* efeat = (const float*)d_in[2];
    const float* inW   = (const float*)d_in[3];
    const float* inb   = (const float*)d_in[4];
    const float* mW1   = (const float*)d_in[5];
    const float* mb1   = (const float*)d_in[6];
    const float* mW2   = (const float*)d_in[7];
    const float* mb2   = (const float*)d_in[8];
    const float* uW1   = (const float*)d_in[9];
    const float* ub1   = (const float*)d_in[10];
    const float* uW2   = (const float*)d_in[11];
    const float* ub2   = (const float*)d_in[12];
    const float* outW  = (const float*)d_in[13];
    const float* outb  = (const float*)d_in[14];
    float* outp = (float*)d_out;

    const int MT = NB * NN;   // 40000 batched rows

    char* p = (char*)d_ws;
    auto carve = [&](size_t bytes) -> void* {
        void* r = (void*)p;
        p += (bytes + 255) & ~(size_t)255;
        return r;
    };
    unsigned short* hS  = (unsigned short*)carve((size_t)2 * MT * HDIM * 2);  // hi|lo planes
    unsigned short* T3S = (unsigned short*)carve((size_t)2 * MT * HDIM * 2);
    float* T12 = (float*)carve((size_t)MT * 512 * 4);     // Hs|Hd fused, f32 (82 MB)
    unsigned short* US = (unsigned short*)T12;            // alias: U planes reuse dead T12
    int* csr_src = (int*)carve((size_t)NB * NE * 4);
    int* csr_eid = (int*)carve((size_t)NB * NE * 4);
    int* row_ptr = (int*)carve((size_t)NB * (NN + 1) * 4);
    int* cursor  = (int*)carve((size_t)NB * NN * 4);
    int* cnt     = (int*)carve((size_t)NB * NN * 4);
    float* degf  = (float*)carve((size_t)MT * 4);
    unsigned short* wtbuf  = (unsigned short*)carve((size_t)1638400 * 2);
    unsigned short* w2v1bT = (unsigned short*)carve((size_t)4 * 65536 * 2);
    float* b2v     = (float*)carve((size_t)4 * 256 * 4);
    float* bias512 = (float*)carve((size_t)4 * 512 * 4);
    (void)ws_size; (void)in_sizes; (void)n_in; (void)out_size;

    unsigned short* hHi  = hS;   unsigned short* hLo  = hS  + (size_t)MT * HDIM;
    unsigned short* t3Hi = T3S;  unsigned short* t3Lo = T3S + (size_t)MT * HDIM;
    unsigned short* uHi  = US;   unsigned short* uLo  = US  + (size_t)MT * HDIM;

    const dim3 blk(256);
    const dim3 gIn(625, 2), gHsHd(625, 4), gU(625, 2), gRes(625, 2), gOut(625, 1);
    const dim3 gE(NB * NN / 4);   // 10000, both graphs

    // once: weight transforms
    tr_k<<<dim3(17, 8, 18), blk, 0, stream>>>(inW, mW1, mW2, uW1, uW2, outW, wtbuf);
    wv_k<<<dim3(16, 16, 4), blk, 0, stream>>>(mW2, uW1, w2v1bT);
    bv_k<<<dim3(4), dim3(512), 0, stream>>>(mb1, mb2, uW1, b2v, bias512);

    const unsigned short* wtIn  = wtbuf;
    const unsigned short* wtW1  = wtbuf + 16384;
    const unsigned short* wtU1  = wtbuf + 835584;
    const unsigned short* wtU2  = wtbuf + 1359872;
    const unsigned short* wtOut = wtbuf + 1622016;

    // CSR for both graphs
    hipMemsetAsync(cnt, 0, (size_t)NB * NN * sizeof(int), stream);
    for (int g = 0; g < NB; ++g) {
        const int* ei_g = ei + (size_t)g * NE * 2;
        hist_k<<<(NE + 255) / 256, blk, 0, stream>>>(ei_g, cnt + g * NN);
        scan_k<<<1, blk, 0, stream>>>(cnt + g * NN, row_ptr + g * (NN + 1),
                                      cursor + g * NN, degf + g * NN);
        fill_k<<<(NE + 255) / 256, blk, 0, stream>>>(ei_g, cursor + g * NN,
                                                     csr_src + (size_t)g * NE,
                                                     csr_eid + (size_t)g * NE);
    }

    // h = nf @ in_W + in_b  (batched M=40000) -> split planes
    mgemm_k<0, 0, 1><<<gIn, blk, 0, stream>>>(
        nf, nullptr, nullptr, wtIn, NDIM,
        nullptr, nullptr, nullptr, 0,
        inb, nullptr, nullptr,
        nullptr, hHi, hLo, MT, HDIM, NDIM, 0, 0);

    for (int l = 0; l < NL; ++l) {
        const unsigned short* w1t = wtW1 + (size_t)l * 139264;
        const unsigned short* u1t = wtU1 + (size_t)l * 131072;
        const unsigned short* u2t = wtU2 + (size_t)l * 65536;

        // T12 = h @ [W1a|W1b] + [0,b1]   (batched, fused N=512)
        mgemm_k<0, 1, 0><<<gHsHd, blk, 0, stream>>>(
            nullptr, hHi, hLo, w1t, 544,
            nullptr, nullptr, nullptr, 0,
            bias512 + l * 512, nullptr, nullptr,
            T12, nullptr, nullptr, MT, 512, HDIM, 0, 256);

        // Sagg (fused Ef MFMA + aggregate, both graphs) -> T3 split planes
        edge_agg4_k<<<gE, blk, 0, stream>>>(T12, efeat, w1t,
                                            csr_src, csr_eid, row_ptr,
                                            t3Hi, t3Lo);

        // U = gelu(h@V1a + Sagg@(W2@V1b) + deg*(b2@V1b) + c1) -> US (aliases T12)
        mgemm_k<4, 1, 1><<<gU, blk, 0, stream>>>(
            nullptr, hHi, hLo, u1t, 512,
            t3Hi, t3Lo, w2v1bT + (size_t)l * 65536, 256,
            ub1 + l * HDIM, b2v + l * 256, degf,
            nullptr, uHi, uLo, MT, HDIM, HDIM, HDIM, 0);

        // h = h + U@V2 + c2  -> split planes
        mgemm_k<3, 1, 1><<<gRes, blk, 0, stream>>>(
            nullptr, uHi, uLo, u2t, HDIM,
            nullptr, nullptr, nullptr, 0,
            ub2 + l * HDIM, nullptr, nullptr,
            nullptr, hHi, hLo, MT, HDIM, HDIM, 0, 0);
    }

    // out = h @ out_W + out_b (f32, batched)
    mgemm_k<0, 1, 0><<<gOut, blk, 0, stream>>>(
        nullptr, hHi, hLo, wtOut, HDIM,
        nullptr, nullptr, nullptr, 0,
        outb, nullptr, nullptr,
        outp, nullptr, nullptr, MT, NDIM, HDIM, 0, 0);
}

// Round 8
// 1328.285 us; speedup vs baseline: 3.1109x; 1.1831x over previous
//
#include <hip/hip_runtime.h>

#define NN 20000     // nodes per graph
#define NE 320000    // edges per graph
#define NB 2         // graphs
#define HDIM 256     // hidden
#define NDIM 64      // node feature dim
#define EDIM 32      // edge feature dim
#define NL 4         // layers

typedef short short8 __attribute__((ext_vector_type(8)));
typedef float f32x4 __attribute__((ext_vector_type(4)));

// gelu(x) = x * sigmoid(2*0.7978...*(x+0.044715x^3)) = x - x/(e+1),
// e = exp2(2.3022082*(x+0.044715x^3)).  8 VALU incl 2 trans.
__device__ __forceinline__ float gelu_af(float x) {
    float x3 = x * x * x;
    float e = exp2f(2.3022082f * fmaf(0.044715f, x3, x));
    return fmaf(-x, __builtin_amdgcn_rcpf(e + 1.0f), x);
}

__device__ __forceinline__ unsigned short f2bf(float f) {
    unsigned int x = __float_as_uint(f);
    unsigned int r = (x + 0x7fffu + ((x >> 16) & 1u)) >> 16;
    return (unsigned short)r;
}
__device__ __forceinline__ float bf2f(unsigned short h) {
    return __uint_as_float(((unsigned int)h) << 16);
}

// ---------------- weight transpose + bf16 convert (once per launch) ---------
__global__ __launch_bounds__(256) void tr_k(
    const float* __restrict__ inW, const float* __restrict__ mW1,
    const float* __restrict__ mW2, const float* __restrict__ uW1,
    const float* __restrict__ uW2, const float* __restrict__ outW,
    unsigned short* __restrict__ dst)
{
    const int id = blockIdx.z;
    const float* src; int K, N; size_t doff;
    if (id == 0)       { src = inW;  K = 64;  N = 256; doff = 0; }
    else if (id <= 4)  { int l = id - 1;  src = mW1 + (size_t)l * 544 * 256; K = 544; N = 256; doff = 16384   + (size_t)l * 139264; }
    else if (id <= 8)  { int l = id - 5;  src = mW2 + (size_t)l * 256 * 256; K = 256; N = 256; doff = 573440  + (size_t)l * 65536;  }
    else if (id <= 12) { int l = id - 9;  src = uW1 + (size_t)l * 512 * 256; K = 512; N = 256; doff = 835584  + (size_t)l * 131072; }
    else if (id <= 16) { int l = id - 13; src = uW2 + (size_t)l * 256 * 256; K = 256; N = 256; doff = 1359872 + (size_t)l * 65536;  }
    else               { src = outW; K = 256; N = 64;  doff = 1622016; }

    const int k0 = blockIdx.x * 32, n0 = blockIdx.y * 32;
    if (k0 >= K || n0 >= N) return;   // block-uniform

    __shared__ float tile[32][33];
    const int tx = threadIdx.x & 31, ty = threadIdx.x >> 5;
    #pragma unroll
    for (int i = 0; i < 4; ++i) {
        int k = k0 + ty + i * 8, n = n0 + tx;
        tile[ty + i * 8][tx] = (k < K && n < N) ? src[(size_t)k * N + n] : 0.f;
    }
    __syncthreads();
    #pragma unroll
    for (int i = 0; i < 4; ++i) {
        int n = n0 + ty + i * 8, k = k0 + tx;
        if (n < N && k < K) dst[doff + (size_t)n * K + k] = f2bf(tile[tx][ty + i * 8]);
    }
}

// ---------------- W2@V1b precompute: WT[n][k] = sum_j W2[k][j] V1b[j][n] ----
__global__ __launch_bounds__(256) void wv_k(
    const float* __restrict__ mW2, const float* __restrict__ uW1,
    unsigned short* __restrict__ w2v1bT)
{
    const int l = blockIdx.z;
    const float* W2  = mW2 + (size_t)l * 65536;
    const float* V1b = uW1 + (size_t)l * 131072 + 65536;   // rows 256.. of [512][256]
    const int n0 = blockIdx.x * 16, k0 = blockIdx.y * 16;
    const int tx = threadIdx.x & 15, ty = threadIdx.x >> 4;
    __shared__ float sW[16][17], sV[16][17];
    float acc = 0.f;
    for (int j0 = 0; j0 < 256; j0 += 16) {
        sW[ty][tx] = W2[(size_t)(k0 + ty) * 256 + j0 + tx];
        sV[ty][tx] = V1b[(size_t)(j0 + ty) * 256 + n0 + tx];
        __syncthreads();
        #pragma unroll
        for (int jj = 0; jj < 16; ++jj)
            acc = fmaf(sW[ty][jj], sV[jj][tx], acc);
        __syncthreads();
    }
    w2v1bT[(size_t)l * 65536 + (size_t)(n0 + tx) * 256 + (k0 + ty)] = f2bf(acc);
}

// ---------------- b2@V1b + fused bias512 build ------------------------------
__global__ void bv_k(const float* __restrict__ mb1, const float* __restrict__ mb2,
                     const float* __restrict__ uW1,
                     float* __restrict__ b2v, float* __restrict__ bias512)
{
    const int l = blockIdx.x, t = threadIdx.x;   // 512 threads
    if (t < 256) {
        const float* V1b = uW1 + (size_t)l * 131072 + 65536;
        const float* b2  = mb2 + l * 256;
        float s = 0.f;
        for (int j = 0; j < 256; ++j) s = fmaf(b2[j], V1b[(size_t)j * 256 + t], s);
        b2v[l * 256 + t] = s;
    }
    bias512[l * 512 + t] = (t < 256) ? 0.f : mb1[l * 256 + (t - 256)];
}

// ---------------- MFMA GEMM ------------------------------------------------
// ASPLIT=0: A is f32, runtime hi/lo split.  ASPLIT=1: A (and A2) pre-split planes.
// CSPLIT=0: C f32.  CSPLIT=1: C hi/lo bf16 planes (Ch/Cl).
// MODE 0: C = A@W + bias(optional)
// MODE 3: C = (Chi+Clo) + A@W + bias      (residual; A != C buffers)
// MODE 4: C = gelu(A@W + A2@W2 + degf[m]*bias2 + bias)
template <int MODE, int ASPLIT, int CSPLIT>
__global__ __launch_bounds__(256) void mgemm_k(
    const float* __restrict__ A,
    const unsigned short* __restrict__ Ah, const unsigned short* __restrict__ Al,
    const unsigned short* __restrict__ BT, int ldb,
    const unsigned short* __restrict__ A2h, const unsigned short* __restrict__ A2l,
    const unsigned short* __restrict__ BT2, int ldb2,
    const float* __restrict__ bias, const float* __restrict__ bias2,
    const float* __restrict__ degf,
    float* __restrict__ C, unsigned short* __restrict__ Ch, unsigned short* __restrict__ Cl,
    int M, int N, int K, int K2, int bkoff)
{
    __shared__ unsigned char smem[64 * 80 * 2 + 128 * 80];  // ahi, alo, bt (80B rows)
    unsigned char* ahi = smem;
    unsigned char* alo = smem + 64 * 80;
    unsigned char* btl = smem + 64 * 80 * 2;

    const int tid = threadIdx.x;
    const int bm = blockIdx.x * 64;
    const int bn = blockIdx.y * 128;
    const int w = tid >> 6, lane = tid & 63;
    const int wr = w >> 1, wc = w & 1;
    const int lrow = lane & 15, lg = lane >> 4;

    f32x4 acc[2][4];
    #pragma unroll
    for (int i = 0; i < 2; ++i)
        #pragma unroll
        for (int j = 0; j < 4; ++j) acc[i][j] = (f32x4){0.f, 0.f, 0.f, 0.f};

    const int t1 = K >> 5, t2 = K2 >> 5;
    for (int t = 0; t < t1 + t2; ++t) {
        int k0, lda, ldbv;
        const float* Ap; const unsigned short* Ahp; const unsigned short* Alp;
        const unsigned short* Bp;
        if (t < t1) { Ap = A;  Ahp = Ah;  Alp = Al;  Bp = BT;  k0 = t * 32;        lda = K;  ldbv = ldb;  }
        else        { Ap = nullptr; Ahp = A2h; Alp = A2l; Bp = BT2; k0 = (t - t1) * 32; lda = K2; ldbv = ldb2; }

        {   // stage A
            const int row = tid >> 2, kq = (tid & 3) * 8;
            const int m = bm + row;
            if (ASPLIT) {
                uint4 hv = make_uint4(0u, 0u, 0u, 0u), lv = hv;
                if (m < M) {
                    hv = *(const uint4*)&Ahp[(size_t)m * lda + k0 + kq];
                    lv = *(const uint4*)&Alp[(size_t)m * lda + k0 + kq];
                }
                *(uint4*)(ahi + row * 80 + kq * 2) = hv;
                *(uint4*)(alo + row * 80 + kq * 2) = lv;
            } else {
                float4 v0 = make_float4(0.f, 0.f, 0.f, 0.f), v1 = v0;
                if (m < M) {
                    v0 = *(const float4*)&Ap[(size_t)m * lda + k0 + kq];
                    v1 = *(const float4*)&Ap[(size_t)m * lda + k0 + kq + 4];
                }
                float vv[8] = {v0.x, v0.y, v0.z, v0.w, v1.x, v1.y, v1.z, v1.w};
                unsigned short hh[8], ll[8];
                #pragma unroll
                for (int j = 0; j < 8; ++j) {
                    hh[j] = f2bf(vv[j]);
                    ll[j] = f2bf(vv[j] - bf2f(hh[j]));
                }
                ushort4 ph0 = {hh[0], hh[1], hh[2], hh[3]}, ph1 = {hh[4], hh[5], hh[6], hh[7]};
                ushort4 pl0 = {ll[0], ll[1], ll[2], ll[3]}, pl1 = {ll[4], ll[5], ll[6], ll[7]};
                *(ushort4*)(ahi + row * 80 + kq * 2)     = ph0;
                *(ushort4*)(ahi + row * 80 + kq * 2 + 8) = ph1;
                *(ushort4*)(alo + row * 80 + kq * 2)     = pl0;
                *(ushort4*)(alo + row * 80 + kq * 2 + 8) = pl1;
            }
        }
        {   // stage B: 128 n-rows x 32 k bf16; fused-B via (n>>8)*bkoff column shift
            const int row = tid >> 1, half = tid & 1;
            const int n = bn + row;
            const unsigned short* brow = Bp + (size_t)(n & 255) * ldbv + (n >> 8) * bkoff;
            #pragma unroll
            for (int c = 0; c < 2; ++c) {
                const int q = half * 2 + c;
                uint4 d = make_uint4(0u, 0u, 0u, 0u);
                if (n < N) d = *(const uint4*)&brow[k0 + q * 8];
                *(uint4*)(btl + row * 80 + q * 16) = d;
            }
        }
        __syncthreads();

        short8 ah[2], al[2], bfr[4];
        #pragma unroll
        for (int mi = 0; mi < 2; ++mi) {
            const int r = wr * 32 + mi * 16 + lrow;
            ah[mi] = *(const short8*)(ahi + r * 80 + lg * 16);
            al[mi] = *(const short8*)(alo + r * 80 + lg * 16);
        }
        #pragma unroll
        for (int ni = 0; ni < 4; ++ni) {
            const int r = wc * 64 + ni * 16 + lrow;
            bfr[ni] = *(const short8*)(btl + r * 80 + lg * 16);
        }
        #pragma unroll
        for (int mi = 0; mi < 2; ++mi)
            #pragma unroll
            for (int ni = 0; ni < 4; ++ni) {
                acc[mi][ni] = __builtin_amdgcn_mfma_f32_16x16x32_bf16(ah[mi], bfr[ni], acc[mi][ni], 0, 0, 0);
                acc[mi][ni] = __builtin_amdgcn_mfma_f32_16x16x32_bf16(al[mi], bfr[ni], acc[mi][ni], 0, 0, 0);
            }
        __syncthreads();
    }

    // epilogue: D row = 4*lg + reg, col = lrow
    #pragma unroll
    for (int mi = 0; mi < 2; ++mi) {
        #pragma unroll
        for (int ni = 0; ni < 4; ++ni) {
            const int ncol = bn + wc * 64 + ni * 16 + lrow;
            if (ncol >= N) continue;
            const float bv = bias ? bias[ncol] : 0.f;
            const float b2vv = (MODE == 4) ? bias2[ncol] : 0.f;
            const int mbase = bm + wr * 32 + mi * 16 + lg * 4;
            #pragma unroll
            for (int r = 0; r < 4; ++r) {
                const int m = mbase + r;
                if (m >= M) continue;
                const size_t cb = (size_t)m * N + ncol;
                float v = acc[mi][ni][r];
                if (MODE == 0)      v += bv;
                else if (MODE == 3) v += bf2f(Ch[cb]) + bf2f(Cl[cb]) + bv;
                else                v = gelu_af(v + degf[m] * b2vv + bv);
                if (CSPLIT) {
                    unsigned short hi = f2bf(v);
                    unsigned short lo = f2bf(v - bf2f(hi));
                    Ch[cb] = hi; Cl[cb] = lo;
                } else {
                    C[cb] = v;
                }
            }
        }
    }
}

// ---------------- CSR build (counting sort by destination), batched ---------
__global__ void hist2_k(const int* __restrict__ ei, int* __restrict__ cnt) {
    int i = blockIdx.x * blockDim.x + threadIdx.x;
    if (i < NB * NE) {
        const int g = i / NE, e = i - g * NE;
        atomicAdd(&cnt[g * NN + ei[(size_t)g * NE * 2 + 2 * e + 1]], 1);
    }
}

__global__ void scan2_k(const int* __restrict__ cnt_all, int* __restrict__ row_ptr_all,
                        int* __restrict__ cursor_all, float* __restrict__ degf_all) {
    const int g = blockIdx.x;
    const int* cnt = cnt_all + g * NN;
    int* row_ptr = row_ptr_all + g * (NN + 1);
    int* cursor  = cursor_all + g * NN;
    float* degf  = degf_all + g * NN;
    __shared__ int part[256];
    int tid = threadIdx.x;
    const int per = (NN + 255) >> 8;
    int s0 = tid * per;
    int s1 = s0 + per; if (s1 > NN) s1 = NN; if (s0 > NN) s0 = NN;
    int sum = 0;
    for (int i = s0; i < s1; ++i) sum += cnt[i];
    part[tid] = sum;
    __syncthreads();
    if (tid == 0) {
        int r = 0;
        for (int i = 0; i < 256; ++i) { int v = part[i]; part[i] = r; r += v; }
    }
    __syncthreads();
    int off = part[tid];
    for (int i = s0; i < s1; ++i) {
        int c = cnt[i];
        row_ptr[i] = off; cursor[i] = off; degf[i] = (float)c;
        off += c;
    }
    if (tid == 255) row_ptr[NN] = off;
}

__global__ void fill2_k(const int* __restrict__ ei, int* __restrict__ cursor,
                        int* __restrict__ csr_src, int* __restrict__ csr_eid) {
    int i = blockIdx.x * blockDim.x + threadIdx.x;
    if (i < NB * NE) {
        const int g = i / NE, e = i - g * NE;
        const int* eig = ei + (size_t)g * NE * 2;
        int s = eig[2 * e + 0];
        int d = eig[2 * e + 1];
        int pos = atomicAdd(&cursor[g * NN + d], 1);
        csr_src[(size_t)g * NE + pos] = s;
        csr_eid[(size_t)g * NE + pos] = e;
    }
}

// ---------------- Edge aggregation v5: per-wave autonomous, zero barriers ---
// Wave owns node d; iterates its CSR range in 16-position chunks:
//  - A fragment (16 gathered efeat rows, bf16) built in registers from global
//  - W1c B-fragments register-resident (16 x short8)
//  - Ef chunk -> per-wave LDS slab (16 x 260 shorts)
//  - consume with 4-wide gather ILP; src ids distributed via __shfl
// Sagg[d] = sum_p gelu(T12[src_p][0:256] + T12[d][256:512] + Ef[p]) -> split bf16
__global__ __launch_bounds__(256, 4) void edge_agg5_k(
    const float* __restrict__ T12, const float* __restrict__ efeat,
    const unsigned short* __restrict__ w1t,   // [256][544] bf16, W1c at col 512
    const int* __restrict__ csr_src, const int* __restrict__ csr_eid,
    const int* __restrict__ row_ptr,
    unsigned short* __restrict__ Shi, unsigned short* __restrict__ Slo)
{
    __shared__ unsigned short efo[4][16 * 260];   // 33280 B total

    const int tid = threadIdx.x;
    const int g   = blockIdx.x / (NN / 4);
    const int blk = blockIdx.x % (NN / 4);
    const int wave = tid >> 6, lane = tid & 63;
    const int lrow = lane & 15, lg = lane >> 4;
    const int d = blk * 4 + wave;

    const float* T12g = T12 + (size_t)g * NN * 512;
    const float* efg  = efeat + (size_t)g * NE * EDIM;
    const int* csG    = csr_src + (size_t)g * NE;
    const int* ceG    = csr_eid + (size_t)g * NE;
    const int* rpG    = row_ptr + (size_t)g * (NN + 1);

    const int dstart = rpG[d], dend = rpG[d + 1];
    const int c0 = lane * 4;

    // W1c^T B-fragments in registers: tile ni covers cols ni*16+lrow (64 VGPR)
    short8 bfrag[16];
    #pragma unroll
    for (int ni = 0; ni < 16; ++ni)
        bfrag[ni] = *(const short8*)&w1t[(size_t)(ni * 16 + lrow) * 544 + 512 + lg * 8];

    const float4 hd = *(const float4*)&T12g[(size_t)d * 512 + 256 + c0];
    float4 acc = make_float4(0.f, 0.f, 0.f, 0.f);
    unsigned short* efw = &efo[wave][0];

    for (int P = dstart; P < dend; P += 16) {
        const int nv = dend - P < 16 ? dend - P : 16;
        int pos = P + lrow; if (pos >= dend) pos = dend - 1;

        // per-lane loads: this chunk's eid (row lrow) and src id (for shfl)
        const int eid  = ceG[pos];
        const int myid = csG[pos];

        // A fragment: row lrow = position, k = lg*8..+7 (bf16 from global)
        const float* er = &efg[(size_t)eid * EDIM + lg * 8];
        float4 v0 = *(const float4*)er;
        float4 v1 = *(const float4*)(er + 4);
        short8 af;
        af[0] = (short)f2bf(v0.x); af[1] = (short)f2bf(v0.y);
        af[2] = (short)f2bf(v0.z); af[3] = (short)f2bf(v0.w);
        af[4] = (short)f2bf(v1.x); af[5] = (short)f2bf(v1.y);
        af[6] = (short)f2bf(v1.z); af[7] = (short)f2bf(v1.w);

        // 16 MFMAs -> Ef chunk in per-wave LDS (D: row=4lg+r, col=ni*16+lrow)
        #pragma unroll
        for (int ni = 0; ni < 16; ++ni) {
            f32x4 a4 = (f32x4){0.f, 0.f, 0.f, 0.f};
            a4 = __builtin_amdgcn_mfma_f32_16x16x32_bf16(af, bfrag[ni], a4, 0, 0, 0);
            #pragma unroll
            for (int r = 0; r < 4; ++r)
                efw[(4 * lg + r) * 260 + ni * 16 + lrow] = f2bf(a4[r]);
        }

        // consume nv positions, 4-wide gather ILP (no barriers: same-wave LDS)
        for (int p = P; p < P + nv; p += 4) {
            const int nc = P + nv - p;
            int sj[4]; float4 hs[4]; ushort4 ef4[4];
            #pragma unroll
            for (int j = 0; j < 4; ++j) {
                const int q = p + ((j < nc) ? j : 0);
                sj[j] = __shfl(myid, q - P, 64);
            }
            #pragma unroll
            for (int j = 0; j < 4; ++j) {
                const int q = p + ((j < nc) ? j : 0);
                hs[j] = *(const float4*)&T12g[(size_t)sj[j] * 512 + c0];
                ef4[j] = *(const ushort4*)&efw[(q - P) * 260 + c0];
            }
            #pragma unroll
            for (int j = 0; j < 4; ++j) {
                if (j < nc) {   // wave-uniform predicate
                    acc.x += gelu_af(hs[j].x + hd.x + bf2f(ef4[j].x));
                    acc.y += gelu_af(hs[j].y + hd.y + bf2f(ef4[j].y));
                    acc.z += gelu_af(hs[j].z + hd.z + bf2f(ef4[j].z));
                    acc.w += gelu_af(hs[j].w + hd.w + bf2f(ef4[j].w));
                }
            }
        }
    }

    ushort4 ho, lo;
    ho.x = f2bf(acc.x); lo.x = f2bf(acc.x - bf2f(ho.x));
    ho.y = f2bf(acc.y); lo.y = f2bf(acc.y - bf2f(ho.y));
    ho.z = f2bf(acc.z); lo.z = f2bf(acc.z - bf2f(ho.z));
    ho.w = f2bf(acc.w); lo.w = f2bf(acc.w - bf2f(ho.w));
    *(ushort4*)&Shi[((size_t)g * NN + d) * HDIM + c0] = ho;
    *(ushort4*)&Slo[((size_t)g * NN + d) * HDIM + c0] = lo;
}

// ---------------- launcher ---------------------------------------------------
extern "C" void kernel_launch(void* const* d_in, const int* in_sizes, int n_in,
                              void* d_out, int out_size, void* d_ws, size_t ws_size,
                              hipStream_t stream)
{
    const float* nf    = (const float*)d_in[0];
    const int*   ei    = (const int*)  d_in[1];
    const float* efeat = (const float*)d_in[2];
    const float* inW   = (const float*)d_in[3];
    const float* inb   = (const float*)d_in[4];
    const float* mW1   = (const float*)d_in[5];
    const float* mb1   = (const float*)d_in[6];
    const float* mW2   = (const float*)d_in[7];
    const float* mb2   = (const float*)d_in[8];
    const float* uW1   = (const float*)d_in[9];
    const float* ub1   = (const float*)d_in[10];
    const float* uW2   = (const float*)d_in[11];
    const float* ub2   = (const float*)d_in[12];
    const float* outW  = (const float*)d_in[13];
    const float* outb  = (const float*)d_in[14];
    float* outp = (float*)d_out;

    const int MT = NB * NN;   // 40000 batched rows

    char* p = (char*)d_ws;
    auto carve = [&](size_t bytes) -> void* {
        void* r = (void*)p;
        p += (bytes + 255) & ~(size_t)255;
        return r;
    };
    unsigned short* hS  = (unsigned short*)carve((size_t)2 * MT * HDIM * 2);  // hi|lo planes
    unsigned short* T3S = (unsigned short*)carve((size_t)2 * MT * HDIM * 2);
    float* T12 = (float*)carve((size_t)MT * 512 * 4);     // Hs|Hd fused, f32 (82 MB)
    unsigned short* US = (unsigned short*)T12;            // alias: U planes reuse dead T12
    int* csr_src = (int*)carve((size_t)NB * NE * 4);
    int* csr_eid = (int*)carve((size_t)NB * NE * 4);
    int* row_ptr = (int*)carve((size_t)NB * (NN + 1) * 4);
    int* cursor  = (int*)carve((size_t)NB * NN * 4);
    int* cnt     = (int*)carve((size_t)NB * NN * 4);
    float* degf  = (float*)carve((size_t)MT * 4);
    unsigned short* wtbuf  = (unsigned short*)carve((size_t)1638400 * 2);
    unsigned short* w2v1bT = (unsigned short*)carve((size_t)4 * 65536 * 2);
    float* b2v     = (float*)carve((size_t)4 * 256 * 4);
    float* bias512 = (float*)carve((size_t)4 * 512 * 4);
    (void)ws_size; (void)in_sizes; (void)n_in; (void)out_size;

    unsigned short* hHi  = hS;   unsigned short* hLo  = hS  + (size_t)MT * HDIM;
    unsigned short* t3Hi = T3S;  unsigned short* t3Lo = T3S + (size_t)MT * HDIM;
    unsigned short* uHi  = US;   unsigned short* uLo  = US  + (size_t)MT * HDIM;

    const dim3 blk(256);
    const dim3 gIn(625, 2), gHsHd(625, 4), gU(625, 2), gRes(625, 2), gOut(625, 1);
    const dim3 gE(NB * NN / 4);   // 10000, both graphs

    // once: weight transforms
    tr_k<<<dim3(17, 8, 18), blk, 0, stream>>>(inW, mW1, mW2, uW1, uW2, outW, wtbuf);
    wv_k<<<dim3(16, 16, 4), blk, 0, stream>>>(mW2, uW1, w2v1bT);
    bv_k<<<dim3(4), dim3(512), 0, stream>>>(mb1, mb2, uW1, b2v, bias512);

    const unsigned short* wtIn  = wtbuf;
    const unsigned short* wtW1  = wtbuf + 16384;
    const unsigned short* wtU1  = wtbuf + 835584;
    const unsigned short* wtU2  = wtbuf + 1359872;
    const unsigned short* wtOut = wtbuf + 1622016;

    // CSR for both graphs (batched)
    hipMemsetAsync(cnt, 0, (size_t)NB * NN * sizeof(int), stream);
    hist2_k<<<(NB * NE + 255) / 256, blk, 0, stream>>>(ei, cnt);
    scan2_k<<<dim3(NB), blk, 0, stream>>>(cnt, row_ptr, cursor, degf);
    fill2_k<<<(NB * NE + 255) / 256, blk, 0, stream>>>(ei, cursor, csr_src, csr_eid);

    // h = nf @ in_W + in_b  (batched M=40000) -> split planes
    mgemm_k<0, 0, 1><<<gIn, blk, 0, stream>>>(
        nf, nullptr, nullptr, wtIn, NDIM,
        nullptr, nullptr, nullptr, 0,
        inb, nullptr, nullptr,
        nullptr, hHi, hLo, MT, HDIM, NDIM, 0, 0);

    for (int l = 0; l < NL; ++l) {
        const unsigned short* w1t = wtW1 + (size_t)l * 139264;
        const unsigned short* u1t = wtU1 + (size_t)l * 131072;
        const unsigned short* u2t = wtU2 + (size_t)l * 65536;

        // T12 = h @ [W1a|W1b] + [0,b1]   (batched, fused N=512)
        mgemm_k<0, 1, 0><<<gHsHd, blk, 0, stream>>>(
            nullptr, hHi, hLo, w1t, 544,
            nullptr, nullptr, nullptr, 0,
            bias512 + l * 512, nullptr, nullptr,
            T12, nullptr, nullptr, MT, 512, HDIM, 0, 256);

        // Sagg (fused Ef MFMA + aggregate, both graphs) -> T3 split planes
        edge_agg5_k<<<gE, blk, 0, stream>>>(T12, efeat, w1t,
                                            csr_src, csr_eid, row_ptr,
                                            t3Hi, t3Lo);

        // U = gelu(h@V1a + Sagg@(W2@V1b) + deg*(b2@V1b) + c1) -> US (aliases T12)
        mgemm_k<4, 1, 1><<<gU, blk, 0, stream>>>(
            nullptr, hHi, hLo, u1t, 512,
            t3Hi, t3Lo, w2v1bT + (size_t)l * 65536, 256,
            ub1 + l * HDIM, b2v + l * 256, degf,
            nullptr, uHi, uLo, MT, HDIM, HDIM, HDIM, 0);

        // h = h + U@V2 + c2  -> split planes
        mgemm_k<3, 1, 1><<<gRes, blk, 0, stream>>>(
            nullptr, uHi, uLo, u2t, HDIM,
            nullptr, nullptr, nullptr, 0,
            ub2 + l * HDIM, nullptr, nullptr,
            nullptr, hHi, hLo, MT, HDIM, HDIM, 0, 0);
    }

    // out = h @ out_W + out_b (f32, batched)
    mgemm_k<0, 1, 0><<<gOut, blk, 0, stream>>>(
        nullptr, hHi, hLo, wtOut, HDIM,
        nullptr, nullptr, nullptr, 0,
        outb, nullptr, nullptr,
        outp, nullptr, nullptr, MT, NDIM, HDIM, 0, 0);
}